// Round 1
// baseline (752.875 us; speedup 1.0000x reference)
//
#include <hip/hip_runtime.h>
#include <hip/hip_bf16.h>

#define NB 65536

// ---------------------------------------------------------------------------
// Kernel 1: fused 5-layer MLP.  32 rows per WG, 256 threads.
// Activations live in LDS [32][256], XOR-swizzled (col ^ (row&15)) so the
// per-k column reads (16 lanes, consecutive rows, stride 256) hit 16 distinct
// banks instead of one.  Weights are streamed from global (L2-resident,
// broadcast across the 16 lanes that share a column group) as float4.
// Each thread computes a 2-row x (N/16)-col register tile; all loop bounds are
// compile-time so accumulators stay in registers.
// ---------------------------------------------------------------------------

template<int K, int N, bool RELU, bool LAST>
__device__ inline void mlp_layer(const float* __restrict__ W,
                                 const float* __restrict__ bias,
                                 const float* __restrict__ bufIn,
                                 float* __restrict__ bufOut,
                                 float* __restrict__ qout,
                                 int tid, int r0)
{
    constexpr int CPT = N / 16;          // columns per thread
    const int r   = tid & 15;            // rows r and r+16
    const int cg  = tid >> 4;            // 0..15
    const int c0  = cg * CPT;
    const int swz = r;                   // (r&15) == ((r+16)&15)

    float acc0[CPT], acc1[CPT];
#pragma unroll
    for (int j = 0; j < CPT; ++j) { float b = bias[c0 + j]; acc0[j] = b; acc1[j] = b; }

    const float* rowIn0 = bufIn + r * 256;
    const float* rowIn1 = bufIn + (r + 16) * 256;

#pragma unroll 2
    for (int k = 0; k < K; ++k) {
        float a0 = rowIn0[k ^ swz];
        float a1 = rowIn1[k ^ swz];
        const float* wrow = W + k * N + c0;
        float w[CPT];
        if constexpr (CPT >= 4) {
#pragma unroll
            for (int jj = 0; jj < CPT / 4; ++jj) {
                float4 v = reinterpret_cast<const float4*>(wrow)[jj];
                w[jj*4+0] = v.x; w[jj*4+1] = v.y; w[jj*4+2] = v.z; w[jj*4+3] = v.w;
            }
        } else {
            float2 v = reinterpret_cast<const float2*>(wrow)[0];
            w[0] = v.x; w[1] = v.y;
        }
#pragma unroll
        for (int j = 0; j < CPT; ++j) { acc0[j] += a0 * w[j]; acc1[j] += a1 * w[j]; }
    }

#pragma unroll
    for (int j = 0; j < CPT; ++j) {
        float v0 = acc0[j], v1 = acc1[j];
        if (RELU) { v0 = fmaxf(v0, 0.f); v1 = fmaxf(v1, 0.f); }
        int c = c0 + j;
        if (LAST) {
            qout[(r0 + r) * 32 + c]      = v0;
            qout[(r0 + r + 16) * 32 + c] = v1;
        } else {
            bufOut[r * 256 + (c ^ swz)]        = v0;
            bufOut[(r + 16) * 256 + (c ^ swz)] = v1;
        }
    }
}

__global__ void __launch_bounds__(256) mlp_kernel(
    const float* __restrict__ hid,
    const float* __restrict__ qw0, const float* __restrict__ qb0,
    const float* __restrict__ qw1, const float* __restrict__ qb1,
    const float* __restrict__ qw2, const float* __restrict__ qb2,
    const float* __restrict__ qw3, const float* __restrict__ qb3,
    const float* __restrict__ qw4, const float* __restrict__ qb4,
    float* __restrict__ qout)
{
    __shared__ float bufA[32 * 256];
    __shared__ float bufB[32 * 256];
    const int tid = threadIdx.x;
    const int r0  = blockIdx.x * 32;

#pragma unroll
    for (int i = 0; i < 32; ++i) {
        int idx = i * 256 + tid;          // row i, col tid  (coalesced)
        bufA[i * 256 + (tid ^ (i & 15))] = hid[r0 * 256 + idx];
    }
    __syncthreads();
    mlp_layer<256, 256, true,  false>(qw0, qb0, bufA, bufB, nullptr, tid, r0);
    __syncthreads();
    mlp_layer<256, 128, true,  false>(qw1, qb1, bufB, bufA, nullptr, tid, r0);
    __syncthreads();
    mlp_layer<128,  64, true,  false>(qw2, qb2, bufA, bufB, nullptr, tid, r0);
    __syncthreads();
    mlp_layer< 64,  32, true,  false>(qw3, qb3, bufB, bufA, nullptr, tid, r0);
    __syncthreads();
    mlp_layer< 32,  32, false, true >(qw4, qb4, bufA, nullptr, qout, tid, r0);
}

// ---------------------------------------------------------------------------
// Kernel 2: conv1 + conv2 + K/V assembly + attention + head.
// One wave (64 lanes) per batch element, 4 elements per 256-thread WG.
// Everything per-element lives in LDS; conv/attention weights are staged in
// LDS once per WG; head weights read straight through L1/L2 (tiny, hot).
// ---------------------------------------------------------------------------

__global__ void __launch_bounds__(256) fused_kernel(
    const float* __restrict__ X,
    const float* __restrict__ c1w_g, const float* __restrict__ c1b_g,
    const float* __restrict__ c2w_g, const float* __restrict__ c2b_g,
    const float* __restrict__ aw0,   const float* __restrict__ ab0,
    const float* __restrict__ aw1,   const float* __restrict__ ab1,
    const float* __restrict__ qws,
    float* __restrict__ out)
{
    __shared__ float s_c1w[600], s_c1b[8], s_c2w[864], s_c2b[12], s_S[100];
    __shared__ float s_X[4][148];
    __shared__ float s_O1[4][200];
    __shared__ float s_K[4][200];
    __shared__ float s_V[4][304];
    __shared__ float s_q[4][32];
    __shared__ float s_A[4][100];
    __shared__ float s_a[4][48];
    __shared__ float s_h1[4][32];

    const int tid  = threadIdx.x;
    const int wv   = tid >> 6;
    const int lane = tid & 63;
    const int e    = blockIdx.x * 4 + wv;

    // --- WG-shared weights + spatial basis ---
    for (int i = tid; i < 600; i += 256) s_c1w[i] = c1w_g[i];
    for (int i = tid; i < 864; i += 256) s_c2w[i] = c2w_g[i];
    if (tid < 8)                 s_c1b[tid]      = c1b_g[tid];
    if (tid >= 32 && tid < 44)   s_c2b[tid - 32] = c2b_g[tid - 32];
    if (tid >= 64 && tid < 164) {
        int i = tid - 64;
        int p = i >> 2, k = i & 3;
        int h = p / 5, w = p % 5;
        int u = (k >> 1) + 1, v = (k & 1) + 1;
        const float PI5 = 0.6283185307179586f;
        s_S[i] = cosf(((float)(h + 1) * PI5) * (float)u) *
                 cosf(((float)(w + 1) * PI5) * (float)v);
    }

    // --- per-element inputs ---
    for (int i = lane; i < 147; i += 64) s_X[wv][i] = X[e * 147 + i];
    if (lane < 32) s_q[wv][lane] = qws[e * 32 + lane];
    __syncthreads();

    // --- conv1: 5x5x3 -> 8ch over 5x5 outputs (pad 1) ---
    for (int o = lane; o < 200; o += 64) {
        int c = o & 7, p = o >> 3;
        int y = p / 5, x = p - 5 * y;
        float acc = s_c1b[c];
#pragma unroll
        for (int ky = 0; ky < 5; ++ky) {
            int iy = y - 1 + ky;
            if ((unsigned)iy < 7u) {
#pragma unroll
                for (int kx = 0; kx < 5; ++kx) {
                    int ix = x - 1 + kx;
                    if ((unsigned)ix < 7u) {
                        const float* xp = &s_X[wv][(iy * 7 + ix) * 3];
                        const float* wp = &s_c1w[((ky * 5 + kx) * 3) * 8 + c];
                        acc += xp[0] * wp[0] + xp[1] * wp[8] + xp[2] * wp[16];
                    }
                }
            }
        }
        s_O1[wv][o] = acc;   // o == p*8+c
    }
    __syncthreads();

    // --- conv2: 3x3x8 -> 12ch, writes K (ch0..3) and V (ch4..11) ---
    for (int o = lane; o < 300; o += 64) {
        int p = o / 12, c = o - 12 * p;
        int y = p / 5, x = p - 5 * y;
        float acc = s_c2b[c];
#pragma unroll
        for (int ky = 0; ky < 3; ++ky) {
            int iy = y - 1 + ky;
            if ((unsigned)iy < 5u) {
#pragma unroll
                for (int kx = 0; kx < 3; ++kx) {
                    int ix = x - 1 + kx;
                    if ((unsigned)ix < 5u) {
                        const float* op = &s_O1[wv][(iy * 5 + ix) * 8];
                        const float* wp = &s_c2w[((ky * 3 + kx) * 8) * 12 + c];
#pragma unroll
                        for (int ci = 0; ci < 8; ++ci) acc += op[ci] * wp[ci * 12];
                    }
                }
            }
        }
        if (c < 4) s_K[wv][p * 8 + c] = acc;
        else       s_V[wv][p * 12 + (c - 4)] = acc;
    }
    // spatial basis into K[4..7], V[8..11]
    for (int o = lane; o < 100; o += 64) {
        int p = o >> 2, k = o & 3;
        float s = s_S[o];
        s_K[wv][p * 8 + 4 + k]  = s;
        s_V[wv][p * 12 + 8 + k] = s;
    }
    __syncthreads();

    // --- logits: A[qi][p] = sum_k K[p][k]*q[qi][k] ---
    for (int o = lane; o < 100; o += 64) {
        int p = o >> 2, qi = o & 3;
        float acc = 0.f;
#pragma unroll
        for (int k = 0; k < 8; ++k) acc += s_K[wv][p * 8 + k] * s_q[wv][qi * 8 + k];
        s_A[wv][qi * 25 + p] = acc;
    }
    __syncthreads();

    // --- softmax over the 25 positions, one lane per query ---
    if (lane < 4) {
        float* Ar = &s_A[wv][lane * 25];
        float m = Ar[0];
        for (int p = 1; p < 25; ++p) m = fmaxf(m, Ar[p]);
        float sum = 0.f;
        for (int p = 0; p < 25; ++p) { float ev = expf(Ar[p] - m); Ar[p] = ev; sum += ev; }
        float inv = 1.f / sum;
        for (int p = 0; p < 25; ++p) Ar[p] *= inv;
    }
    __syncthreads();

    // --- a[qi][d] = sum_p A[qi][p] * V[p][d] ---
    if (lane < 48) {
        int qi = lane / 12, d = lane - 12 * qi;
        float acc = 0.f;
#pragma unroll
        for (int p = 0; p < 25; ++p) acc += s_A[wv][qi * 25 + p] * s_V[wv][p * 12 + d];
        s_a[wv][lane] = acc;
    }
    __syncthreads();

    // --- head layer 1: h1[j] = relu(ab0[j] + sum_i a[i]*aw0[i][j]) ---
    if (lane < 32) {
        float acc = ab0[lane];
#pragma unroll
        for (int i = 0; i < 48; ++i) acc += s_a[wv][i] * aw0[i * 32 + lane];
        s_h1[wv][lane] = fmaxf(acc, 0.f);
    }
    __syncthreads();

    // --- head layer 2: out[o] = ab1[o] + sum_j h1[j]*aw1[j][o] ---
    {
        float acc = ab1[lane];
#pragma unroll
        for (int j = 0; j < 32; ++j) acc += s_h1[wv][j] * aw1[j * 64 + lane];
        out[e * 64 + lane] = acc;
    }
}

// ---------------------------------------------------------------------------

extern "C" void kernel_launch(void* const* d_in, const int* in_sizes, int n_in,
                              void* d_out, int out_size, void* d_ws, size_t ws_size,
                              hipStream_t stream)
{
    const float* X   = (const float*)d_in[0];
    const float* hid = (const float*)d_in[1];
    const float* c1w = (const float*)d_in[2];
    const float* c1b = (const float*)d_in[3];
    const float* c2w = (const float*)d_in[4];
    const float* c2b = (const float*)d_in[5];
    const float* qw0 = (const float*)d_in[6];
    const float* qb0 = (const float*)d_in[7];
    const float* qw1 = (const float*)d_in[8];
    const float* qb1 = (const float*)d_in[9];
    const float* qw2 = (const float*)d_in[10];
    const float* qb2 = (const float*)d_in[11];
    const float* qw3 = (const float*)d_in[12];
    const float* qb3 = (const float*)d_in[13];
    const float* qw4 = (const float*)d_in[14];
    const float* qb4 = (const float*)d_in[15];
    const float* aw0 = (const float*)d_in[16];
    const float* ab0 = (const float*)d_in[17];
    const float* aw1 = (const float*)d_in[18];
    const float* ab1 = (const float*)d_in[19];

    float* out  = (float*)d_out;
    float* qbuf = (float*)d_ws;   // NB x 32 floats = 8.4 MB of scratch

    hipLaunchKernelGGL(mlp_kernel, dim3(NB / 32), dim3(256), 0, stream,
                       hid, qw0, qb0, qw1, qb1, qw2, qb2, qw3, qb3, qw4, qb4, qbuf);
    hipLaunchKernelGGL(fused_kernel, dim3(NB / 4), dim3(256), 0, stream,
                       X, c1w, c1b, c2w, c2b, aw0, ab0, aw1, ab1, qbuf, out);
}

// Round 2
// 437.548 us; speedup vs baseline: 1.7207x; 1.7207x over previous
//
#include <hip/hip_runtime.h>
#include <hip/hip_bf16.h>

#define NB 65536

typedef __attribute__((ext_vector_type(8))) short short8;
typedef __attribute__((ext_vector_type(4))) float f32x4;

__device__ inline short f2bf(float f) {
    unsigned u = __builtin_bit_cast(unsigned, f);
    unsigned r = (u + 0x7fffu + ((u >> 16) & 1u)) >> 16;   // RNE
    return (short)(unsigned short)r;
}
__device__ inline float b2f(short s) {
    return __builtin_bit_cast(float, (unsigned)((unsigned short)s) << 16);
}

// ---------------------------------------------------------------------------
// Kernel 0: weight prep — transpose qw0..qw4 (fp32 [K][N]) into bf16 [N][K]
// so MFMA B-fragments (col fixed, k contiguous) are single 16B loads.
// ---------------------------------------------------------------------------
__global__ void __launch_bounds__(256) prep_kernel(
    const float* __restrict__ w0, const float* __restrict__ w1,
    const float* __restrict__ w2, const float* __restrict__ w3,
    const float* __restrict__ w4, short* __restrict__ wt)
{
    const int stride = gridDim.x * 256;
    for (int idx = blockIdx.x * 256 + threadIdx.x; idx < 109568; idx += stride) {
        float v;
        if (idx < 65536) {            // L0: K=256,N=256
            int l = idx;            int n = l >> 8;  int k = l & 255;
            v = w0[k * 256 + n];
        } else if (idx < 98304) {     // L1: K=256,N=128
            int l = idx - 65536;    int n = l >> 8;  int k = l & 255;
            v = w1[k * 128 + n];
        } else if (idx < 106496) {    // L2: K=128,N=64
            int l = idx - 98304;    int n = l >> 7;  int k = l & 127;
            v = w2[k * 64 + n];
        } else if (idx < 108544) {    // L3: K=64,N=32
            int l = idx - 106496;   int n = l >> 6;  int k = l & 63;
            v = w3[k * 32 + n];
        } else {                      // L4: K=32,N=32
            int l = idx - 108544;   int n = l >> 5;  int k = l & 31;
            v = w4[k * 32 + n];
        }
        wt[idx] = f2bf(v);
    }
}

// ---------------------------------------------------------------------------
// Kernel 1: fused 5-layer MLP via bf16 MFMA.  32 rows/WG, 256 threads
// (4 waves as 2m x 2n).  Activations in LDS bf16, 16B-chunk XOR swizzle
// (chunk ^= row&MASK) so A-fragment ds_read_b128 is ~2-way max conflict.
// Weights stream from L2 (transposed bf16), bias fp32 from global.
// ---------------------------------------------------------------------------

template<int K, int N, bool RELU, bool LAST>
__device__ inline void layerT(const short* __restrict__ WT,   // [N][K] bf16
                              const float* __restrict__ bias, // [N] fp32
                              const short* __restrict__ lIn,  // LDS [32][K]
                              short* __restrict__ lOut,       // LDS [32][N]
                              short* __restrict__ qout,       // LAST: global bf16 [B][32]
                              int wv, int lane, int r0)
{
    constexpr int KT = K / 32;            // k-tiles (MFMA depth 32)
    constexpr int NT = N / 32;            // n-tiles per wave (2-way n split)
    constexpr int MASKI = (K / 8 - 1) & 7;
    constexpr int MASKO = (N / 8 - 1) & 7;
    const int m0    = (wv & 1) * 16;
    const int nbase = (wv >> 1) * (N / 2);
    const int row   = m0 + (lane & 15);
    const int g     = lane >> 4;

    // A fragments for this wave's 16-row strip, reused across all n-tiles.
    short8 af[KT];
#pragma unroll
    for (int kt = 0; kt < KT; ++kt) {
        int phys = (kt * 4 + g) ^ (row & MASKI);
        af[kt] = *(const short8*)(lIn + row * K + phys * 8);
    }

#pragma unroll
    for (int nt = 0; nt < NT; ++nt) {
        const int n = nbase + nt * 16 + (lane & 15);
        float b = bias[n];
        f32x4 acc; acc[0] = b; acc[1] = b; acc[2] = b; acc[3] = b;
        const short* wrow = WT + n * K + g * 8;
#pragma unroll
        for (int kt = 0; kt < KT; ++kt) {
            short8 bf = *(const short8*)(wrow + kt * 32);
            acc = __builtin_amdgcn_mfma_f32_16x16x32_bf16(af[kt], bf, acc, 0, 0, 0);
        }
#pragma unroll
        for (int j = 0; j < 4; ++j) {
            int m = m0 + g * 4 + j;              // C/D: col=lane&15, row=g*4+j
            float v = acc[j];
            if (RELU) v = fmaxf(v, 0.f);
            if (LAST) {
                qout[(r0 + m) * 32 + n] = f2bf(v);
            } else {
                int phys = ((n >> 3) ^ (m & MASKO));
                lOut[m * N + phys * 8 + (n & 7)] = f2bf(v);
            }
        }
    }
}

__global__ void __launch_bounds__(256) mlp_kernel(
    const float* __restrict__ hid,
    const float* __restrict__ qb0, const float* __restrict__ qb1,
    const float* __restrict__ qb2, const float* __restrict__ qb3,
    const float* __restrict__ qb4,
    const short* __restrict__ wsW,
    short* __restrict__ qout)
{
    __shared__ short lA[32 * 256];
    __shared__ short lB[32 * 256];
    const int tid  = threadIdx.x;
    const int wv   = tid >> 6;
    const int lane = tid & 63;
    const int r0   = blockIdx.x * 32;

    // Stage hid (fp32) -> lA (bf16, swizzled).  32 rows x 32 chunks of 8 cols.
#pragma unroll
    for (int i = 0; i < 4; ++i) {
        int cid = tid + 256 * i;
        int rrow = cid >> 5, ch = cid & 31;
        const float* src = hid + (r0 + rrow) * 256 + ch * 8;
        float4 v0 = reinterpret_cast<const float4*>(src)[0];
        float4 v1 = reinterpret_cast<const float4*>(src)[1];
        short8 s;
        s[0] = f2bf(v0.x); s[1] = f2bf(v0.y); s[2] = f2bf(v0.z); s[3] = f2bf(v0.w);
        s[4] = f2bf(v1.x); s[5] = f2bf(v1.y); s[6] = f2bf(v1.z); s[7] = f2bf(v1.w);
        int phys = ch ^ (rrow & 7);
        *(short8*)(lA + rrow * 256 + phys * 8) = s;
    }
    __syncthreads();

    layerT<256, 256, true,  false>(wsW,          qb0, lA, lB, nullptr, wv, lane, r0);
    __syncthreads();
    layerT<256, 128, true,  false>(wsW + 65536,  qb1, lB, lA, nullptr, wv, lane, r0);
    __syncthreads();
    layerT<128,  64, true,  false>(wsW + 98304,  qb2, lA, lB, nullptr, wv, lane, r0);
    __syncthreads();
    layerT< 64,  32, true,  false>(wsW + 106496, qb3, lB, lA, nullptr, wv, lane, r0);
    __syncthreads();
    layerT< 32,  32, false, true >(wsW + 108544, qb4, lA, nullptr, qout, wv, lane, r0);
}

// ---------------------------------------------------------------------------
// Kernel 2: conv1 + conv2 + K/V assembly + attention + head (unchanged from
// R0 except q is now read as bf16).
// ---------------------------------------------------------------------------

__global__ void __launch_bounds__(256) fused_kernel(
    const float* __restrict__ X,
    const float* __restrict__ c1w_g, const float* __restrict__ c1b_g,
    const float* __restrict__ c2w_g, const float* __restrict__ c2b_g,
    const float* __restrict__ aw0,   const float* __restrict__ ab0,
    const float* __restrict__ aw1,   const float* __restrict__ ab1,
    const short* __restrict__ qws,
    float* __restrict__ out)
{
    __shared__ float s_c1w[600], s_c1b[8], s_c2w[864], s_c2b[12], s_S[100];
    __shared__ float s_X[4][148];
    __shared__ float s_O1[4][200];
    __shared__ float s_K[4][200];
    __shared__ float s_V[4][304];
    __shared__ float s_q[4][32];
    __shared__ float s_A[4][100];
    __shared__ float s_a[4][48];
    __shared__ float s_h1[4][32];

    const int tid  = threadIdx.x;
    const int wv   = tid >> 6;
    const int lane = tid & 63;
    const int e    = blockIdx.x * 4 + wv;

    for (int i = tid; i < 600; i += 256) s_c1w[i] = c1w_g[i];
    for (int i = tid; i < 864; i += 256) s_c2w[i] = c2w_g[i];
    if (tid < 8)                 s_c1b[tid]      = c1b_g[tid];
    if (tid >= 32 && tid < 44)   s_c2b[tid - 32] = c2b_g[tid - 32];
    if (tid >= 64 && tid < 164) {
        int i = tid - 64;
        int p = i >> 2, k = i & 3;
        int h = p / 5, w = p % 5;
        int u = (k >> 1) + 1, v = (k & 1) + 1;
        const float PI5 = 0.6283185307179586f;
        s_S[i] = cosf(((float)(h + 1) * PI5) * (float)u) *
                 cosf(((float)(w + 1) * PI5) * (float)v);
    }

    for (int i = lane; i < 147; i += 64) s_X[wv][i] = X[e * 147 + i];
    if (lane < 32) s_q[wv][lane] = b2f(qws[e * 32 + lane]);
    __syncthreads();

    // conv1: 5x5x3 -> 8ch
    for (int o = lane; o < 200; o += 64) {
        int c = o & 7, p = o >> 3;
        int y = p / 5, x = p - 5 * y;
        float acc = s_c1b[c];
#pragma unroll
        for (int ky = 0; ky < 5; ++ky) {
            int iy = y - 1 + ky;
            if ((unsigned)iy < 7u) {
#pragma unroll
                for (int kx = 0; kx < 5; ++kx) {
                    int ix = x - 1 + kx;
                    if ((unsigned)ix < 7u) {
                        const float* xp = &s_X[wv][(iy * 7 + ix) * 3];
                        const float* wp = &s_c1w[((ky * 5 + kx) * 3) * 8 + c];
                        acc += xp[0] * wp[0] + xp[1] * wp[8] + xp[2] * wp[16];
                    }
                }
            }
        }
        s_O1[wv][o] = acc;
    }
    __syncthreads();

    // conv2: 3x3x8 -> 12ch  (K = ch0..3, V = ch4..11)
    for (int o = lane; o < 300; o += 64) {
        int p = o / 12, c = o - 12 * p;
        int y = p / 5, x = p - 5 * y;
        float acc = s_c2b[c];
#pragma unroll
        for (int ky = 0; ky < 3; ++ky) {
            int iy = y - 1 + ky;
            if ((unsigned)iy < 5u) {
#pragma unroll
                for (int kx = 0; kx < 3; ++kx) {
                    int ix = x - 1 + kx;
                    if ((unsigned)ix < 5u) {
                        const float* op = &s_O1[wv][(iy * 5 + ix) * 8];
                        const float* wp = &s_c2w[((ky * 3 + kx) * 8) * 12 + c];
#pragma unroll
                        for (int ci = 0; ci < 8; ++ci) acc += op[ci] * wp[ci * 12];
                    }
                }
            }
        }
        if (c < 4) s_K[wv][p * 8 + c] = acc;
        else       s_V[wv][p * 12 + (c - 4)] = acc;
    }
    for (int o = lane; o < 100; o += 64) {
        int p = o >> 2, k = o & 3;
        float s = s_S[o];
        s_K[wv][p * 8 + 4 + k]  = s;
        s_V[wv][p * 12 + 8 + k] = s;
    }
    __syncthreads();

    // logits
    for (int o = lane; o < 100; o += 64) {
        int p = o >> 2, qi = o & 3;
        float acc = 0.f;
#pragma unroll
        for (int k = 0; k < 8; ++k) acc += s_K[wv][p * 8 + k] * s_q[wv][qi * 8 + k];
        s_A[wv][qi * 25 + p] = acc;
    }
    __syncthreads();

    // softmax (one lane per query)
    if (lane < 4) {
        float* Ar = &s_A[wv][lane * 25];
        float m = Ar[0];
        for (int p = 1; p < 25; ++p) m = fmaxf(m, Ar[p]);
        float sum = 0.f;
        for (int p = 0; p < 25; ++p) { float ev = expf(Ar[p] - m); Ar[p] = ev; sum += ev; }
        float inv = 1.f / sum;
        for (int p = 0; p < 25; ++p) Ar[p] *= inv;
    }
    __syncthreads();

    // a = A @ V
    if (lane < 48) {
        int qi = lane / 12, d = lane - 12 * qi;
        float acc = 0.f;
#pragma unroll
        for (int p = 0; p < 25; ++p) acc += s_A[wv][qi * 25 + p] * s_V[wv][p * 12 + d];
        s_a[wv][lane] = acc;
    }
    __syncthreads();

    // head layer 1
    if (lane < 32) {
        float acc = ab0[lane];
#pragma unroll
        for (int i = 0; i < 48; ++i) acc += s_a[wv][i] * aw0[i * 32 + lane];
        s_h1[wv][lane] = fmaxf(acc, 0.f);
    }
    __syncthreads();

    // head layer 2
    {
        float acc = ab1[lane];
#pragma unroll
        for (int j = 0; j < 32; ++j) acc += s_h1[wv][j] * aw1[j * 64 + lane];
        out[e * 64 + lane] = acc;
    }
}

// ---------------------------------------------------------------------------

extern "C" void kernel_launch(void* const* d_in, const int* in_sizes, int n_in,
                              void* d_out, int out_size, void* d_ws, size_t ws_size,
                              hipStream_t stream)
{
    const float* X   = (const float*)d_in[0];
    const float* hid = (const float*)d_in[1];
    const float* c1w = (const float*)d_in[2];
    const float* c1b = (const float*)d_in[3];
    const float* c2w = (const float*)d_in[4];
    const float* c2b = (const float*)d_in[5];
    const float* qw0 = (const float*)d_in[6];
    const float* qb0 = (const float*)d_in[7];
    const float* qw1 = (const float*)d_in[8];
    const float* qb1 = (const float*)d_in[9];
    const float* qw2 = (const float*)d_in[10];
    const float* qb2 = (const float*)d_in[11];
    const float* qw3 = (const float*)d_in[12];
    const float* qb3 = (const float*)d_in[13];
    const float* qw4 = (const float*)d_in[14];
    const float* qb4 = (const float*)d_in[15];
    const float* aw0 = (const float*)d_in[16];
    const float* ab0 = (const float*)d_in[17];
    const float* aw1 = (const float*)d_in[18];
    const float* ab1 = (const float*)d_in[19];

    float* out  = (float*)d_out;
    short* qb16 = (short*)d_ws;                 // NB*32 bf16 = 4.19 MB
    short* wsW  = qb16 + (size_t)NB * 32;       // 219 KB transposed bf16 weights

    hipLaunchKernelGGL(prep_kernel, dim3(128), dim3(256), 0, stream,
                       qw0, qw1, qw2, qw3, qw4, wsW);
    hipLaunchKernelGGL(mlp_kernel, dim3(NB / 32), dim3(256), 0, stream,
                       hid, qb0, qb1, qb2, qb3, qb4, wsW, qb16);
    hipLaunchKernelGGL(fused_kernel, dim3(NB / 4), dim3(256), 0, stream,
                       X, c1w, c1b, c2w, c2b, aw0, ab0, aw1, ab1, qb16, out);
}

// Round 3
// 199.552 us; speedup vs baseline: 3.7728x; 2.1927x over previous
//
#include <hip/hip_runtime.h>
#include <hip/hip_bf16.h>

#define NB 65536

typedef __attribute__((ext_vector_type(8))) short short8;
typedef __attribute__((ext_vector_type(4))) short short4v;
typedef __attribute__((ext_vector_type(4))) float f32x4;

__device__ inline short f2bf(float f) {
    unsigned u = __builtin_bit_cast(unsigned, f);
    unsigned r = (u + 0x7fffu + ((u >> 16) & 1u)) >> 16;   // RNE
    return (short)(unsigned short)r;
}
__device__ inline float b2f(short s) {
    return __builtin_bit_cast(float, (unsigned)((unsigned short)s) << 16);
}

// ws layout (shorts unless noted):
//   qb16  : NB*32                      @ 0
//   wsW   : 109568 (MLP weights^T)     @ NB*32
//   weffT : 51200  (320 x 160 bf16)    @ +109568
//   beff  : 320 f32                    @ +51200 (cast)
#define MLPW_CNT 109568
#define WEFF_CNT 51200

// ---------------------------------------------------------------------------
// Kernel 0: prep — (a) MLP weights -> bf16 [N][K]; (b) composed conv weight
// Weff^T bf16 [320][160]; (c) effective bias beff f32 [320].
// ---------------------------------------------------------------------------
__global__ void __launch_bounds__(256) prep_kernel(
    const float* __restrict__ w0, const float* __restrict__ w1,
    const float* __restrict__ w2, const float* __restrict__ w3,
    const float* __restrict__ w4,
    const float* __restrict__ c1w, const float* __restrict__ c1b,
    const float* __restrict__ c2w, const float* __restrict__ c2b,
    short* __restrict__ wt, short* __restrict__ weff, float* __restrict__ beff)
{
    int idx = blockIdx.x * 256 + threadIdx.x;
    if (idx < MLPW_CNT) {
        float v;
        if (idx < 65536) {            // L0: K=256,N=256
            int l = idx;            int n = l >> 8;  int k = l & 255;
            v = w0[k * 256 + n];
        } else if (idx < 98304) {     // L1: K=256,N=128
            int l = idx - 65536;    int n = l >> 8;  int k = l & 255;
            v = w1[k * 128 + n];
        } else if (idx < 106496) {    // L2: K=128,N=64
            int l = idx - 98304;    int n = l >> 7;  int k = l & 127;
            v = w2[k * 64 + n];
        } else if (idx < 108544) {    // L3: K=64,N=32
            int l = idx - 106496;   int n = l >> 6;  int k = l & 63;
            v = w3[k * 32 + n];
        } else {                      // L4: K=32,N=32
            int l = idx - 108544;   int n = l >> 5;  int k = l & 31;
            v = w4[k * 32 + n];
        }
        wt[idx] = f2bf(v);
    } else if (idx < MLPW_CNT + WEFF_CNT) {
        int it = idx - MLPW_CNT;
        int n = it / 160, k = it - n * 160;
        float acc = 0.f;
        if (n < 300 && k < 147) {
            int oc = n % 12, p = n / 12, oy = p / 5, ox = p - oy * 5;
            int ci = k % 3,  t = k / 3, iy = t / 7, ix = t - iy * 7;
            for (int y = 0; y < 5; ++y) {
                int ky = iy - y + 1, ly = y - oy + 1;
                if ((unsigned)ky < 5u && (unsigned)ly < 3u) {
                    for (int x = 0; x < 5; ++x) {
                        int kx = ix - x + 1, lx = x - ox + 1;
                        if ((unsigned)kx < 5u && (unsigned)lx < 3u) {
                            const float* p1 = c1w + ((ky * 5 + kx) * 3 + ci) * 8;
                            const float* p2 = c2w + ((ly * 3 + lx) * 8) * 12 + oc;
#pragma unroll
                            for (int c = 0; c < 8; ++c) acc += p1[c] * p2[c * 12];
                        }
                    }
                }
            }
        }
        weff[it] = f2bf(acc);
    } else if (idx < MLPW_CNT + WEFF_CNT + 320) {
        int n = idx - MLPW_CNT - WEFF_CNT;
        float acc = 0.f;
        if (n < 300) {
            int oc = n % 12, p = n / 12, oy = p / 5, ox = p - oy * 5;
            acc = c2b[oc];
            for (int y = 0; y < 5; ++y) {
                int ly = y - oy + 1;
                if ((unsigned)ly < 3u) {
                    for (int x = 0; x < 5; ++x) {
                        int lx = x - ox + 1;
                        if ((unsigned)lx < 3u) {
#pragma unroll
                            for (int c = 0; c < 8; ++c)
                                acc += c2w[((ly * 3 + lx) * 8 + c) * 12 + oc] * c1b[c];
                        }
                    }
                }
            }
        }
        beff[n] = acc;
    }
}

// ---------------------------------------------------------------------------
// Kernel 1: fused 5-layer MLP via bf16 MFMA (unchanged from R2, proven).
// ---------------------------------------------------------------------------
template<int K, int N, bool RELU, bool LAST>
__device__ inline void layerT(const short* __restrict__ WT,
                              const float* __restrict__ bias,
                              const short* __restrict__ lIn,
                              short* __restrict__ lOut,
                              short* __restrict__ qout,
                              int wv, int lane, int r0)
{
    constexpr int KT = K / 32;
    constexpr int NT = N / 32;
    constexpr int MASKI = (K / 8 - 1) & 7;
    constexpr int MASKO = (N / 8 - 1) & 7;
    const int m0    = (wv & 1) * 16;
    const int nbase = (wv >> 1) * (N / 2);
    const int row   = m0 + (lane & 15);
    const int g     = lane >> 4;

    short8 af[KT];
#pragma unroll
    for (int kt = 0; kt < KT; ++kt) {
        int phys = (kt * 4 + g) ^ (row & MASKI);
        af[kt] = *(const short8*)(lIn + row * K + phys * 8);
    }

#pragma unroll
    for (int nt = 0; nt < NT; ++nt) {
        const int n = nbase + nt * 16 + (lane & 15);
        float b = bias[n];
        f32x4 acc; acc[0] = b; acc[1] = b; acc[2] = b; acc[3] = b;
        const short* wrow = WT + n * K + g * 8;
#pragma unroll
        for (int kt = 0; kt < KT; ++kt) {
            short8 bf = *(const short8*)(wrow + kt * 32);
            acc = __builtin_amdgcn_mfma_f32_16x16x32_bf16(af[kt], bf, acc, 0, 0, 0);
        }
#pragma unroll
        for (int j = 0; j < 4; ++j) {
            int m = m0 + g * 4 + j;
            float v = acc[j];
            if (RELU) v = fmaxf(v, 0.f);
            if (LAST) {
                qout[(r0 + m) * 32 + n] = f2bf(v);
            } else {
                int phys = ((n >> 3) ^ (m & MASKO));
                lOut[m * N + phys * 8 + (n & 7)] = f2bf(v);
            }
        }
    }
}

__global__ void __launch_bounds__(256) mlp_kernel(
    const float* __restrict__ hid,
    const float* __restrict__ qb0, const float* __restrict__ qb1,
    const float* __restrict__ qb2, const float* __restrict__ qb3,
    const float* __restrict__ qb4,
    const short* __restrict__ wsW,
    short* __restrict__ qout)
{
    __shared__ short lA[32 * 256];
    __shared__ short lB[32 * 256];
    const int tid  = threadIdx.x;
    const int wv   = tid >> 6;
    const int lane = tid & 63;
    const int r0   = blockIdx.x * 32;

#pragma unroll
    for (int i = 0; i < 4; ++i) {
        int cid = tid + 256 * i;
        int rrow = cid >> 5, ch = cid & 31;
        const float* src = hid + (r0 + rrow) * 256 + ch * 8;
        float4 v0 = reinterpret_cast<const float4*>(src)[0];
        float4 v1 = reinterpret_cast<const float4*>(src)[1];
        short8 s;
        s[0] = f2bf(v0.x); s[1] = f2bf(v0.y); s[2] = f2bf(v0.z); s[3] = f2bf(v0.w);
        s[4] = f2bf(v1.x); s[5] = f2bf(v1.y); s[6] = f2bf(v1.z); s[7] = f2bf(v1.w);
        int phys = ch ^ (rrow & 7);
        *(short8*)(lA + rrow * 256 + phys * 8) = s;
    }
    __syncthreads();

    layerT<256, 256, true,  false>(wsW,          qb0, lA, lB, nullptr, wv, lane, r0);
    __syncthreads();
    layerT<256, 128, true,  false>(wsW + 65536,  qb1, lB, lA, nullptr, wv, lane, r0);
    __syncthreads();
    layerT<128,  64, true,  false>(wsW + 98304,  qb2, lA, lB, nullptr, wv, lane, r0);
    __syncthreads();
    layerT< 64,  32, true,  false>(wsW + 106496, qb3, lB, lA, nullptr, wv, lane, r0);
    __syncthreads();
    layerT< 32,  32, false, true >(wsW + 108544, qb4, lA, nullptr, qout, wv, lane, r0);
}

// ---------------------------------------------------------------------------
// Kernel 2: conv-as-GEMM (O = X @ Weff + beff) + attention + head.
// 32 elements/WG, 256 threads (4 waves, n-split GEMM).
// LDS pool (51.6 KB):
//   phase G: X bf16 [32][192] swizzled @0..12288 ; q,S at tail
//   phase E: K bf16 [32][25*8] @0 (el stride 200 sh) ; V bf16 @12800
//            (el stride 408 sh, rows 16 sh: 8 conv + 4 spatial + 4 zero)
//            a f32 @38912 ; h1 f32 @45056 ; q @49152 ; S @51200
// ---------------------------------------------------------------------------
__global__ void __launch_bounds__(256) conv_attn_kernel(
    const float* __restrict__ Xg,
    const short* __restrict__ weffT,
    const float* __restrict__ beff,
    const float* __restrict__ aw0, const float* __restrict__ ab0,
    const float* __restrict__ aw1, const float* __restrict__ ab1,
    const short* __restrict__ qb16,
    float* __restrict__ out)
{
    __shared__ __align__(16) unsigned char spool[51600];
    short* sX  = (short*)spool;
    short* sK  = (short*)spool;
    short* sV  = (short*)(spool + 12800);
    float* sA  = (float*)(spool + 38912);
    float* sH  = (float*)(spool + 45056);
    short* sQ  = (short*)(spool + 49152);
    float* sS  = (float*)(spool + 51200);

    const int tid    = threadIdx.x;
    const int wv     = tid >> 6;
    const int lane   = tid & 63;
    const int lanelo = lane & 15;
    const int g      = lane >> 4;
    const int blk    = blockIdx.x;

    // ---- phase G: stage X (bf16, swizzled, zero-padded to 160 cols) ----
#pragma unroll
    for (int it = 0; it < 20; ++it) {
        int idx = tid + it * 256;              // 5120 = 32 rows x 160 cols
        int row = idx / 160;
        int col = idx - row * 160;
        float v = (col < 147) ? Xg[blk * 4704 + row * 147 + col] : 0.f;
        int ch = col >> 3;
        sX[row * 192 + ((ch ^ (row & 7)) << 3) + (col & 7)] = f2bf(v);
    }
    // stage q (32x32 bf16)
    {
        short4v qv = *(const short4v*)(qb16 + blk * 1024 + tid * 4);
        *(short4v*)(sQ + tid * 4) = qv;
    }
    // spatial basis (100 values)
    if (tid < 100) {
        int p = tid >> 2, k = tid & 3;
        int h = p / 5, w = p - 5 * h;
        int u = (k >> 1) + 1, v = (k & 1) + 1;
        const float PI5 = 0.6283185307179586f;
        sS[tid] = cosf(((float)(h + 1) * PI5) * (float)u) *
                  cosf(((float)(w + 1) * PI5) * (float)v);
    }
    __syncthreads();

    // ---- GEMM: acc[m][nt] over 2 m-tiles x 5 n-tiles x 5 k-tiles ----
    short8 af[2][5];
#pragma unroll
    for (int m = 0; m < 2; ++m)
#pragma unroll
        for (int kt = 0; kt < 5; ++kt) {
            int row = m * 16 + lanelo;
            int phys = (kt * 4 + g) ^ (row & 7);
            af[m][kt] = *(const short8*)(sX + row * 192 + phys * 8);
        }

    f32x4 acc[2][5];
#pragma unroll
    for (int m = 0; m < 2; ++m)
#pragma unroll
        for (int nt = 0; nt < 5; ++nt) {
            acc[m][nt][0] = 0.f; acc[m][nt][1] = 0.f;
            acc[m][nt][2] = 0.f; acc[m][nt][3] = 0.f;
        }

    const short* wbase = weffT + (wv * 80 + lanelo) * 160 + g * 8;
#pragma unroll
    for (int nt = 0; nt < 5; ++nt) {
        const short* wn = wbase + nt * 16 * 160;
#pragma unroll
        for (int kt = 0; kt < 5; ++kt) {
            short8 bf = *(const short8*)(wn + kt * 32);
            acc[0][nt] = __builtin_amdgcn_mfma_f32_16x16x32_bf16(af[0][kt], bf, acc[0][nt], 0, 0, 0);
            acc[1][nt] = __builtin_amdgcn_mfma_f32_16x16x32_bf16(af[1][kt], bf, acc[1][nt], 0, 0, 0);
        }
    }
    __syncthreads();   // all waves done reading sX; K/V region reuses it

    // ---- scatter O + bias into K/V (bf16) ----
    float bv[5];
#pragma unroll
    for (int nt = 0; nt < 5; ++nt) bv[nt] = beff[wv * 80 + nt * 16 + lanelo];
#pragma unroll
    for (int m = 0; m < 2; ++m)
#pragma unroll
        for (int nt = 0; nt < 5; ++nt) {
            int n = wv * 80 + nt * 16 + lanelo;
            if (n < 300) {
                int p = n / 12, c = n - p * 12;
#pragma unroll
                for (int j = 0; j < 4; ++j) {
                    int row = m * 16 + g * 4 + j;
                    float v = acc[m][nt][j] + bv[nt];
                    if (c < 4) sK[row * 200 + p * 8 + c]        = f2bf(v);
                    else       sV[row * 408 + p * 16 + (c - 4)] = f2bf(v);
                }
            }
        }
    // spatial into K[4..8), V[8..12); zero V[12..16)
    for (int i = tid; i < 3200; i += 256) {
        int el = i / 100;
        int r  = i - el * 100;          // r = p*4 + s
        int p  = r >> 2, s = r & 3;
        short sv = f2bf(sS[r]);
        sK[el * 200 + p * 8 + 4 + s]  = sv;
        sV[el * 408 + p * 16 + 8 + s] = sv;
    }
    for (int i = tid; i < 800; i += 256) {
        int el = i / 25, p = i - el * 25;
        short4v z; z[0] = 0; z[1] = 0; z[2] = 0; z[3] = 0;
        *(short4v*)(sV + el * 408 + p * 16 + 12) = z;
    }
    __syncthreads();

    // ---- S1: logits -> softmax -> PV  (thread = (el, qi), 128 active) ----
    if (tid < 128) {
        int el = tid >> 2, qi = tid & 3;
        short8 qv = *(const short8*)(sQ + el * 32 + qi * 8);
        float qf[8];
#pragma unroll
        for (int i = 0; i < 8; ++i) qf[i] = b2f(qv[i]);

        float lg[25];
#pragma unroll
        for (int p = 0; p < 25; ++p) {
            short8 kv = *(const short8*)(sK + el * 200 + p * 8);
            float s = 0.f;
#pragma unroll
            for (int i = 0; i < 8; ++i) s += b2f(kv[i]) * qf[i];
            lg[p] = s;
        }
        float mx = lg[0];
#pragma unroll
        for (int p = 1; p < 25; ++p) mx = fmaxf(mx, lg[p]);
        float sum = 0.f;
#pragma unroll
        for (int p = 0; p < 25; ++p) { lg[p] = __expf(lg[p] - mx); sum += lg[p]; }
        float inv = 1.f / sum;

        float o[12];
#pragma unroll
        for (int d = 0; d < 12; ++d) o[d] = 0.f;
#pragma unroll
        for (int p = 0; p < 25; ++p) {
            float w = lg[p] * inv;
            short8 v0 = *(const short8*)(sV + el * 408 + p * 16);
            short8 v1 = *(const short8*)(sV + el * 408 + p * 16 + 8);
#pragma unroll
            for (int d = 0; d < 8; ++d) o[d] += w * b2f(v0[d]);
#pragma unroll
            for (int d = 0; d < 4; ++d) o[8 + d] += w * b2f(v1[d]);
        }
#pragma unroll
        for (int d = 0; d < 12; ++d) sA[el * 48 + qi * 12 + d] = o[d];
    }
    __syncthreads();

    // ---- S2: h1 = relu(a @ aw0 + ab0)   thread = (el, t8) ----
    {
        int el = tid >> 3, t8 = tid & 7;
        float a4[4];
        float4 b0 = *(const float4*)(ab0 + t8 * 4);
        a4[0] = b0.x; a4[1] = b0.y; a4[2] = b0.z; a4[3] = b0.w;
#pragma unroll
        for (int i = 0; i < 48; ++i) {
            float av = sA[el * 48 + i];
            float4 wv4 = *(const float4*)(aw0 + i * 32 + t8 * 4);
            a4[0] += av * wv4.x; a4[1] += av * wv4.y;
            a4[2] += av * wv4.z; a4[3] += av * wv4.w;
        }
#pragma unroll
        for (int jj = 0; jj < 4; ++jj)
            sH[el * 32 + t8 * 4 + jj] = fmaxf(a4[jj], 0.f);
    }
    __syncthreads();

    // ---- S3: out = h1 @ aw1 + ab1   thread = (el, t8), 8 cols each ----
    {
        int el = tid >> 3, t8 = tid & 7;
        float a8[8];
        float4 b0 = *(const float4*)(ab1 + t8 * 8);
        float4 b1 = *(const float4*)(ab1 + t8 * 8 + 4);
        a8[0] = b0.x; a8[1] = b0.y; a8[2] = b0.z; a8[3] = b0.w;
        a8[4] = b1.x; a8[5] = b1.y; a8[6] = b1.z; a8[7] = b1.w;
#pragma unroll
        for (int j = 0; j < 32; ++j) {
            float hv = sH[el * 32 + j];
            float4 w0v = *(const float4*)(aw1 + j * 64 + t8 * 8);
            float4 w1v = *(const float4*)(aw1 + j * 64 + t8 * 8 + 4);
            a8[0] += hv * w0v.x; a8[1] += hv * w0v.y;
            a8[2] += hv * w0v.z; a8[3] += hv * w0v.w;
            a8[4] += hv * w1v.x; a8[5] += hv * w1v.y;
            a8[6] += hv * w1v.z; a8[7] += hv * w1v.w;
        }
        int e = blk * 32 + el;
        float4 o0; o0.x = a8[0]; o0.y = a8[1]; o0.z = a8[2]; o0.w = a8[3];
        float4 o1; o1.x = a8[4]; o1.y = a8[5]; o1.z = a8[6]; o1.w = a8[7];
        *(float4*)(out + e * 64 + t8 * 8)     = o0;
        *(float4*)(out + e * 64 + t8 * 8 + 4) = o1;
    }
}

// ---------------------------------------------------------------------------

extern "C" void kernel_launch(void* const* d_in, const int* in_sizes, int n_in,
                              void* d_out, int out_size, void* d_ws, size_t ws_size,
                              hipStream_t stream)
{
    const float* X   = (const float*)d_in[0];
    const float* hid = (const float*)d_in[1];
    const float* c1w = (const float*)d_in[2];
    const float* c1b = (const float*)d_in[3];
    const float* c2w = (const float*)d_in[4];
    const float* c2b = (const float*)d_in[5];
    const float* qw0 = (const float*)d_in[6];
    const float* qb0 = (const float*)d_in[7];
    const float* qw1 = (const float*)d_in[8];
    const float* qb1 = (const float*)d_in[9];
    const float* qw2 = (const float*)d_in[10];
    const float* qb2 = (const float*)d_in[11];
    const float* qw3 = (const float*)d_in[12];
    const float* qb3 = (const float*)d_in[13];
    const float* qw4 = (const float*)d_in[14];
    const float* qb4 = (const float*)d_in[15];
    const float* aw0 = (const float*)d_in[16];
    const float* ab0 = (const float*)d_in[17];
    const float* aw1 = (const float*)d_in[18];
    const float* ab1 = (const float*)d_in[19];

    float* out   = (float*)d_out;
    short* qb16  = (short*)d_ws;
    short* wsW   = qb16 + (size_t)NB * 32;
    short* weffT = wsW + MLPW_CNT;
    float* beff  = (float*)(weffT + WEFF_CNT);

    hipLaunchKernelGGL(prep_kernel, dim3(630), dim3(256), 0, stream,
                       qw0, qw1, qw2, qw3, qw4, c1w, c1b, c2w, c2b,
                       wsW, weffT, beff);
    hipLaunchKernelGGL(mlp_kernel, dim3(NB / 32), dim3(256), 0, stream,
                       hid, qb0, qb1, qb2, qb3, qb4, wsW, qb16);
    hipLaunchKernelGGL(conv_attn_kernel, dim3(NB / 32), dim3(256), 0, stream,
                       X, weffT, beff, aw0, ab0, aw1, ab1, qb16, out);
}

// Round 4
// 151.893 us; speedup vs baseline: 4.9566x; 1.3138x over previous
//
#include <hip/hip_runtime.h>
#include <hip/hip_bf16.h>

#define NB 65536

typedef __attribute__((ext_vector_type(8))) short short8;
typedef __attribute__((ext_vector_type(4))) short short4v;
typedef __attribute__((ext_vector_type(4))) float f32x4;

__device__ inline short f2bf(float f) {
    unsigned u = __builtin_bit_cast(unsigned, f);
    unsigned r = (u + 0x7fffu + ((u >> 16) & 1u)) >> 16;   // RNE
    return (short)(unsigned short)r;
}
__device__ inline float b2f(short s) {
    return __builtin_bit_cast(float, (unsigned)((unsigned short)s) << 16);
}

#define MLPW_CNT 109568
#define WEFF_CNT 51200

// ---------------------------------------------------------------------------
// Kernel 0: prep — (a) MLP weights -> bf16 [N][K]; (b) composed conv weight
// Weff^T bf16 [320][160]; (c) effective bias beff f32 [320].
// ---------------------------------------------------------------------------
__global__ void __launch_bounds__(256) prep_kernel(
    const float* __restrict__ w0, const float* __restrict__ w1,
    const float* __restrict__ w2, const float* __restrict__ w3,
    const float* __restrict__ w4,
    const float* __restrict__ c1w, const float* __restrict__ c1b,
    const float* __restrict__ c2w, const float* __restrict__ c2b,
    short* __restrict__ wt, short* __restrict__ weff, float* __restrict__ beff)
{
    int idx = blockIdx.x * 256 + threadIdx.x;
    if (idx < MLPW_CNT) {
        float v;
        if (idx < 65536) {            // L0: K=256,N=256
            int l = idx;            int n = l >> 8;  int k = l & 255;
            v = w0[k * 256 + n];
        } else if (idx < 98304) {     // L1: K=256,N=128
            int l = idx - 65536;    int n = l >> 8;  int k = l & 255;
            v = w1[k * 128 + n];
        } else if (idx < 106496) {    // L2: K=128,N=64
            int l = idx - 98304;    int n = l >> 7;  int k = l & 127;
            v = w2[k * 64 + n];
        } else if (idx < 108544) {    // L3: K=64,N=32
            int l = idx - 106496;   int n = l >> 6;  int k = l & 63;
            v = w3[k * 32 + n];
        } else {                      // L4: K=32,N=32
            int l = idx - 108544;   int n = l >> 5;  int k = l & 31;
            v = w4[k * 32 + n];
        }
        wt[idx] = f2bf(v);
    } else if (idx < MLPW_CNT + WEFF_CNT) {
        int it = idx - MLPW_CNT;
        int n = it / 160, k = it - n * 160;
        float acc = 0.f;
        if (n < 300 && k < 147) {
            int oc = n % 12, p = n / 12, oy = p / 5, ox = p - oy * 5;
            int ci = k % 3,  t = k / 3, iy = t / 7, ix = t - iy * 7;
            for (int y = 0; y < 5; ++y) {
                int ky = iy - y + 1, ly = y - oy + 1;
                if ((unsigned)ky < 5u && (unsigned)ly < 3u) {
                    for (int x = 0; x < 5; ++x) {
                        int kx = ix - x + 1, lx = x - ox + 1;
                        if ((unsigned)kx < 5u && (unsigned)lx < 3u) {
                            const float* p1 = c1w + ((ky * 5 + kx) * 3 + ci) * 8;
                            const float* p2 = c2w + ((ly * 3 + lx) * 8) * 12 + oc;
#pragma unroll
                            for (int c = 0; c < 8; ++c) acc += p1[c] * p2[c * 12];
                        }
                    }
                }
            }
        }
        weff[it] = f2bf(acc);
    } else if (idx < MLPW_CNT + WEFF_CNT + 320) {
        int n = idx - MLPW_CNT - WEFF_CNT;
        float acc = 0.f;
        if (n < 300) {
            int oc = n % 12, p = n / 12, oy = p / 5, ox = p - oy * 5;
            acc = c2b[oc];
            for (int y = 0; y < 5; ++y) {
                int ly = y - oy + 1;
                if ((unsigned)ly < 3u) {
                    for (int x = 0; x < 5; ++x) {
                        int lx = x - ox + 1;
                        if ((unsigned)lx < 3u) {
#pragma unroll
                            for (int c = 0; c < 8; ++c)
                                acc += c2w[((ly * 3 + lx) * 8 + c) * 12 + oc] * c1b[c];
                        }
                    }
                }
            }
        }
        beff[n] = acc;
    }
}

// ---------------------------------------------------------------------------
// Kernel 1: fused 5-layer MLP via bf16 MFMA, v2.
// Each wave: ALL 32 rows (2 m-tiles) x N/4 columns.  B-fragments reused by
// 2 independent MFMA chains and double-buffered across n-tiles (explicit
// prefetch while MFMAs run).  Bias added in epilogue (off the dep chain).
// ---------------------------------------------------------------------------
template<int K, int N, bool RELU, bool LAST>
__device__ inline void layerW(const short* __restrict__ WT,   // [N][K] bf16
                              const float* __restrict__ bias, // [N] fp32
                              const short* __restrict__ lIn,  // LDS [32][K] swz
                              short* __restrict__ lOut,       // LDS [32][N] swz
                              short* __restrict__ qout,       // LAST: global bf16
                              int wv, int lane, int r0)
{
    constexpr int KT  = K / 32;
    constexpr int NTW = (N >= 64) ? (N / 64) : 1;   // 16-col n-tiles per wave
    constexpr int MASKI = (K / 8 - 1) & 7;
    constexpr int MASKO = (N / 8 - 1) & 7;
    const int lanelo = lane & 15;
    const int g      = lane >> 4;
    const int nbase  = (N >= 64) ? wv * (N / 4) : wv * 16;
    if (N < 64 && wv >= 2) return;                  // syncs are at kernel level

    // A fragments for both m-tiles (rows lanelo, 16+lanelo), hoisted.
    short8 af0[KT], af1[KT];
#pragma unroll
    for (int kt = 0; kt < KT; ++kt) {
        int phys = (kt * 4 + g) ^ (lanelo & MASKI);   // (row&MASKI)==(lanelo&MASKI)
        af0[kt] = *(const short8*)(lIn + lanelo * K + phys * 8);
        af1[kt] = *(const short8*)(lIn + (16 + lanelo) * K + phys * 8);
    }

    // bias prefetch (off the critical path)
    float bv[NTW];
#pragma unroll
    for (int nt = 0; nt < NTW; ++nt) bv[nt] = bias[nbase + nt * 16 + lanelo];

    // B double-buffer: prefetch nt=0
    short8 bf[2][KT];
    {
        const short* wb = WT + (nbase + lanelo) * K + g * 8;
#pragma unroll
        for (int kt = 0; kt < KT; ++kt) bf[0][kt] = *(const short8*)(wb + kt * 32);
    }

#pragma unroll
    for (int nt = 0; nt < NTW; ++nt) {
        if (nt + 1 < NTW) {
            const short* wb = WT + (nbase + (nt + 1) * 16 + lanelo) * K + g * 8;
#pragma unroll
            for (int kt = 0; kt < KT; ++kt)
                bf[(nt + 1) & 1][kt] = *(const short8*)(wb + kt * 32);
        }
        f32x4 a0, a1;
        a0[0] = 0.f; a0[1] = 0.f; a0[2] = 0.f; a0[3] = 0.f;
        a1[0] = 0.f; a1[1] = 0.f; a1[2] = 0.f; a1[3] = 0.f;
#pragma unroll
        for (int kt = 0; kt < KT; ++kt) {
            a0 = __builtin_amdgcn_mfma_f32_16x16x32_bf16(af0[kt], bf[nt & 1][kt], a0, 0, 0, 0);
            a1 = __builtin_amdgcn_mfma_f32_16x16x32_bf16(af1[kt], bf[nt & 1][kt], a1, 0, 0, 0);
        }
        const int n = nbase + nt * 16 + lanelo;
#pragma unroll
        for (int j = 0; j < 4; ++j) {
            int m0r = g * 4 + j, m1r = 16 + g * 4 + j;
            float v0 = a0[j] + bv[nt];
            float v1 = a1[j] + bv[nt];
            if (RELU) { v0 = fmaxf(v0, 0.f); v1 = fmaxf(v1, 0.f); }
            if (LAST) {
                qout[(r0 + m0r) * 32 + n] = f2bf(v0);
                qout[(r0 + m1r) * 32 + n] = f2bf(v1);
            } else {
                int p0 = ((n >> 3) ^ (m0r & MASKO));
                int p1 = ((n >> 3) ^ (m1r & MASKO));
                lOut[m0r * N + p0 * 8 + (n & 7)] = f2bf(v0);
                lOut[m1r * N + p1 * 8 + (n & 7)] = f2bf(v1);
            }
        }
    }
}

__global__ void __launch_bounds__(256) mlp_kernel(
    const float* __restrict__ hid,
    const float* __restrict__ qb0, const float* __restrict__ qb1,
    const float* __restrict__ qb2, const float* __restrict__ qb3,
    const float* __restrict__ qb4,
    const short* __restrict__ wsW,
    short* __restrict__ qout)
{
    __shared__ short lA[32 * 256];
    __shared__ short lB[32 * 256];
    const int tid  = threadIdx.x;
    const int wv   = tid >> 6;
    const int lane = tid & 63;
    const int r0   = blockIdx.x * 32;

#pragma unroll
    for (int i = 0; i < 4; ++i) {
        int cid = tid + 256 * i;
        int rrow = cid >> 5, ch = cid & 31;
        const float* src = hid + (r0 + rrow) * 256 + ch * 8;
        float4 v0 = reinterpret_cast<const float4*>(src)[0];
        float4 v1 = reinterpret_cast<const float4*>(src)[1];
        short8 s;
        s[0] = f2bf(v0.x); s[1] = f2bf(v0.y); s[2] = f2bf(v0.z); s[3] = f2bf(v0.w);
        s[4] = f2bf(v1.x); s[5] = f2bf(v1.y); s[6] = f2bf(v1.z); s[7] = f2bf(v1.w);
        int phys = ch ^ (rrow & 7);
        *(short8*)(lA + rrow * 256 + phys * 8) = s;
    }
    __syncthreads();

    layerW<256, 256, true,  false>(wsW,          qb0, lA, lB, nullptr, wv, lane, r0);
    __syncthreads();
    layerW<256, 128, true,  false>(wsW + 65536,  qb1, lB, lA, nullptr, wv, lane, r0);
    __syncthreads();
    layerW<128,  64, true,  false>(wsW + 98304,  qb2, lA, lB, nullptr, wv, lane, r0);
    __syncthreads();
    layerW< 64,  32, true,  false>(wsW + 106496, qb3, lB, lA, nullptr, wv, lane, r0);
    __syncthreads();
    layerW< 32,  32, false, true >(wsW + 108544, qb4, lA, nullptr, qout, wv, lane, r0);
}

// ---------------------------------------------------------------------------
// Kernel 2: conv-as-GEMM (O = X @ Weff + beff) + attention + head.
// (unchanged from R3, proven)
// ---------------------------------------------------------------------------
__global__ void __launch_bounds__(256) conv_attn_kernel(
    const float* __restrict__ Xg,
    const short* __restrict__ weffT,
    const float* __restrict__ beff,
    const float* __restrict__ aw0, const float* __restrict__ ab0,
    const float* __restrict__ aw1, const float* __restrict__ ab1,
    const short* __restrict__ qb16,
    float* __restrict__ out)
{
    __shared__ __align__(16) unsigned char spool[51600];
    short* sX  = (short*)spool;
    short* sK  = (short*)spool;
    short* sV  = (short*)(spool + 12800);
    float* sA  = (float*)(spool + 38912);
    float* sH  = (float*)(spool + 45056);
    short* sQ  = (short*)(spool + 49152);
    float* sS  = (float*)(spool + 51200);

    const int tid    = threadIdx.x;
    const int wv     = tid >> 6;
    const int lane   = tid & 63;
    const int lanelo = lane & 15;
    const int g      = lane >> 4;
    const int blk    = blockIdx.x;

    // ---- phase G: stage X (bf16, swizzled, zero-padded to 160 cols) ----
#pragma unroll
    for (int it = 0; it < 20; ++it) {
        int idx = tid + it * 256;              // 5120 = 32 rows x 160 cols
        int row = idx / 160;
        int col = idx - row * 160;
        float v = (col < 147) ? Xg[blk * 4704 + row * 147 + col] : 0.f;
        int ch = col >> 3;
        sX[row * 192 + ((ch ^ (row & 7)) << 3) + (col & 7)] = f2bf(v);
    }
    {
        short4v qv = *(const short4v*)(qb16 + blk * 1024 + tid * 4);
        *(short4v*)(sQ + tid * 4) = qv;
    }
    if (tid < 100) {
        int p = tid >> 2, k = tid & 3;
        int h = p / 5, w = p - 5 * h;
        int u = (k >> 1) + 1, v = (k & 1) + 1;
        const float PI5 = 0.6283185307179586f;
        sS[tid] = cosf(((float)(h + 1) * PI5) * (float)u) *
                  cosf(((float)(w + 1) * PI5) * (float)v);
    }
    __syncthreads();

    // ---- GEMM: acc[m][nt] over 2 m-tiles x 5 n-tiles x 5 k-tiles ----
    short8 af[2][5];
#pragma unroll
    for (int m = 0; m < 2; ++m)
#pragma unroll
        for (int kt = 0; kt < 5; ++kt) {
            int row = m * 16 + lanelo;
            int phys = (kt * 4 + g) ^ (row & 7);
            af[m][kt] = *(const short8*)(sX + row * 192 + phys * 8);
        }

    f32x4 acc[2][5];
#pragma unroll
    for (int m = 0; m < 2; ++m)
#pragma unroll
        for (int nt = 0; nt < 5; ++nt) {
            acc[m][nt][0] = 0.f; acc[m][nt][1] = 0.f;
            acc[m][nt][2] = 0.f; acc[m][nt][3] = 0.f;
        }

    const short* wbase = weffT + (wv * 80 + lanelo) * 160 + g * 8;
#pragma unroll
    for (int nt = 0; nt < 5; ++nt) {
        const short* wn = wbase + nt * 16 * 160;
#pragma unroll
        for (int kt = 0; kt < 5; ++kt) {
            short8 bf = *(const short8*)(wn + kt * 32);
            acc[0][nt] = __builtin_amdgcn_mfma_f32_16x16x32_bf16(af[0][kt], bf, acc[0][nt], 0, 0, 0);
            acc[1][nt] = __builtin_amdgcn_mfma_f32_16x16x32_bf16(af[1][kt], bf, acc[1][nt], 0, 0, 0);
        }
    }
    __syncthreads();   // all waves done reading sX; K/V region reuses it

    // ---- scatter O + bias into K/V (bf16) ----
    float bv[5];
#pragma unroll
    for (int nt = 0; nt < 5; ++nt) bv[nt] = beff[wv * 80 + nt * 16 + lanelo];
#pragma unroll
    for (int m = 0; m < 2; ++m)
#pragma unroll
        for (int nt = 0; nt < 5; ++nt) {
            int n = wv * 80 + nt * 16 + lanelo;
            if (n < 300) {
                int p = n / 12, c = n - p * 12;
#pragma unroll
                for (int j = 0; j < 4; ++j) {
                    int row = m * 16 + g * 4 + j;
                    float v = acc[m][nt][j] + bv[nt];
                    if (c < 4) sK[row * 200 + p * 8 + c]        = f2bf(v);
                    else       sV[row * 408 + p * 16 + (c - 4)] = f2bf(v);
                }
            }
        }
    for (int i = tid; i < 3200; i += 256) {
        int el = i / 100;
        int r  = i - el * 100;
        int p  = r >> 2, s = r & 3;
        short sv = f2bf(sS[r]);
        sK[el * 200 + p * 8 + 4 + s]  = sv;
        sV[el * 408 + p * 16 + 8 + s] = sv;
    }
    for (int i = tid; i < 800; i += 256) {
        int el = i / 25, p = i - el * 25;
        short4v z; z[0] = 0; z[1] = 0; z[2] = 0; z[3] = 0;
        *(short4v*)(sV + el * 408 + p * 16 + 12) = z;
    }
    __syncthreads();

    // ---- S1: logits -> softmax -> PV  (thread = (el, qi), 128 active) ----
    if (tid < 128) {
        int el = tid >> 2, qi = tid & 3;
        short8 qv = *(const short8*)(sQ + el * 32 + qi * 8);
        float qf[8];
#pragma unroll
        for (int i = 0; i < 8; ++i) qf[i] = b2f(qv[i]);

        float lg[25];
#pragma unroll
        for (int p = 0; p < 25; ++p) {
            short8 kv = *(const short8*)(sK + el * 200 + p * 8);
            float s = 0.f;
#pragma unroll
            for (int i = 0; i < 8; ++i) s += b2f(kv[i]) * qf[i];
            lg[p] = s;
        }
        float mx = lg[0];
#pragma unroll
        for (int p = 1; p < 25; ++p) mx = fmaxf(mx, lg[p]);
        float sum = 0.f;
#pragma unroll
        for (int p = 0; p < 25; ++p) { lg[p] = __expf(lg[p] - mx); sum += lg[p]; }
        float inv = 1.f / sum;

        float o[12];
#pragma unroll
        for (int d = 0; d < 12; ++d) o[d] = 0.f;
#pragma unroll
        for (int p = 0; p < 25; ++p) {
            float w = lg[p] * inv;
            short8 v0 = *(const short8*)(sV + el * 408 + p * 16);
            short8 v1 = *(const short8*)(sV + el * 408 + p * 16 + 8);
#pragma unroll
            for (int d = 0; d < 8; ++d) o[d] += w * b2f(v0[d]);
#pragma unroll
            for (int d = 0; d < 4; ++d) o[8 + d] += w * b2f(v1[d]);
        }
#pragma unroll
        for (int d = 0; d < 12; ++d) sA[el * 48 + qi * 12 + d] = o[d];
    }
    __syncthreads();

    // ---- S2: h1 = relu(a @ aw0 + ab0) ----
    {
        int el = tid >> 3, t8 = tid & 7;
        float a4[4];
        float4 b0 = *(const float4*)(ab0 + t8 * 4);
        a4[0] = b0.x; a4[1] = b0.y; a4[2] = b0.z; a4[3] = b0.w;
#pragma unroll
        for (int i = 0; i < 48; ++i) {
            float av = sA[el * 48 + i];
            float4 wv4 = *(const float4*)(aw0 + i * 32 + t8 * 4);
            a4[0] += av * wv4.x; a4[1] += av * wv4.y;
            a4[2] += av * wv4.z; a4[3] += av * wv4.w;
        }
#pragma unroll
        for (int jj = 0; jj < 4; ++jj)
            sH[el * 32 + t8 * 4 + jj] = fmaxf(a4[jj], 0.f);
    }
    __syncthreads();

    // ---- S3: out = h1 @ aw1 + ab1 ----
    {
        int el = tid >> 3, t8 = tid & 7;
        float a8[8];
        float4 b0 = *(const float4*)(ab1 + t8 * 8);
        float4 b1 = *(const float4*)(ab1 + t8 * 8 + 4);
        a8[0] = b0.x; a8[1] = b0.y; a8[2] = b0.z; a8[3] = b0.w;
        a8[4] = b1.x; a8[5] = b1.y; a8[6] = b1.z; a8[7] = b1.w;
#pragma unroll
        for (int j = 0; j < 32; ++j) {
            float hv = sH[el * 32 + j];
            float4 w0v = *(const float4*)(aw1 + j * 64 + t8 * 8);
            float4 w1v = *(const float4*)(aw1 + j * 64 + t8 * 8 + 4);
            a8[0] += hv * w0v.x; a8[1] += hv * w0v.y;
            a8[2] += hv * w0v.z; a8[3] += hv * w0v.w;
            a8[4] += hv * w1v.x; a8[5] += hv * w1v.y;
            a8[6] += hv * w1v.z; a8[7] += hv * w1v.w;
        }
        int e = blk * 32 + el;
        float4 o0; o0.x = a8[0]; o0.y = a8[1]; o0.z = a8[2]; o0.w = a8[3];
        float4 o1; o1.x = a8[4]; o1.y = a8[5]; o1.z = a8[6]; o1.w = a8[7];
        *(float4*)(out + e * 64 + t8 * 8)     = o0;
        *(float4*)(out + e * 64 + t8 * 8 + 4) = o1;
    }
}

// ---------------------------------------------------------------------------

extern "C" void kernel_launch(void* const* d_in, const int* in_sizes, int n_in,
                              void* d_out, int out_size, void* d_ws, size_t ws_size,
                              hipStream_t stream)
{
    const float* X   = (const float*)d_in[0];
    const float* hid = (const float*)d_in[1];
    const float* c1w = (const float*)d_in[2];
    const float* c1b = (const float*)d_in[3];
    const float* c2w = (const float*)d_in[4];
    const float* c2b = (const float*)d_in[5];
    const float* qw0 = (const float*)d_in[6];
    const float* qb0 = (const float*)d_in[7];
    const float* qw1 = (const float*)d_in[8];
    const float* qb1 = (const float*)d_in[9];
    const float* qw2 = (const float*)d_in[10];
    const float* qb2 = (const float*)d_in[11];
    const float* qw3 = (const float*)d_in[12];
    const float* qb3 = (const float*)d_in[13];
    const float* qw4 = (const float*)d_in[14];
    const float* qb4 = (const float*)d_in[15];
    const float* aw0 = (const float*)d_in[16];
    const float* ab0 = (const float*)d_in[17];
    const float* aw1 = (const float*)d_in[18];
    const float* ab1 = (const float*)d_in[19];

    float* out   = (float*)d_out;
    short* qb16  = (short*)d_ws;
    short* wsW   = qb16 + (size_t)NB * 32;
    short* weffT = wsW + MLPW_CNT;
    float* beff  = (float*)(weffT + WEFF_CNT);

    hipLaunchKernelGGL(prep_kernel, dim3(630), dim3(256), 0, stream,
                       qw0, qw1, qw2, qw3, qw4, c1w, c1b, c2w, c2b,
                       wsW, weffT, beff);
    hipLaunchKernelGGL(mlp_kernel, dim3(NB / 32), dim3(256), 0, stream,
                       hid, qb0, qb1, qb2, qb3, qb4, wsW, qb16);
    hipLaunchKernelGGL(conv_attn_kernel, dim3(NB / 32), dim3(256), 0, stream,
                       X, weffT, beff, aw0, ab0, aw1, ab1, qb16, out);
}

// Round 5
// 148.034 us; speedup vs baseline: 5.0858x; 1.0261x over previous
//
#include <hip/hip_runtime.h>
#include <hip/hip_bf16.h>

#define NB 65536

typedef __attribute__((ext_vector_type(8))) short short8;
typedef __attribute__((ext_vector_type(4))) short short4v;
typedef __attribute__((ext_vector_type(4))) float f32x4;

__device__ inline short f2bf(float f) {
    unsigned u = __builtin_bit_cast(unsigned, f);
    unsigned r = (u + 0x7fffu + ((u >> 16) & 1u)) >> 16;   // RNE
    return (short)(unsigned short)r;
}
__device__ inline float b2f(short s) {
    return __builtin_bit_cast(float, (unsigned)((unsigned short)s) << 16);
}

#define MLPW_CNT 109568
#define WEFF_CNT 51200

// ---------------------------------------------------------------------------
// Kernel 0: prep — (a) MLP weights -> bf16 [N][K]; (b) composed conv weight
// Weff^T bf16 [320][160]; (c) effective bias beff f32 [320].
// ---------------------------------------------------------------------------
__global__ void __launch_bounds__(256) prep_kernel(
    const float* __restrict__ w0, const float* __restrict__ w1,
    const float* __restrict__ w2, const float* __restrict__ w3,
    const float* __restrict__ w4,
    const float* __restrict__ c1w, const float* __restrict__ c1b,
    const float* __restrict__ c2w, const float* __restrict__ c2b,
    short* __restrict__ wt, short* __restrict__ weff, float* __restrict__ beff)
{
    int idx = blockIdx.x * 256 + threadIdx.x;
    if (idx < MLPW_CNT) {
        float v;
        if (idx < 65536) {            // L0: K=256,N=256
            int l = idx;            int n = l >> 8;  int k = l & 255;
            v = w0[k * 256 + n];
        } else if (idx < 98304) {     // L1: K=256,N=128
            int l = idx - 65536;    int n = l >> 8;  int k = l & 255;
            v = w1[k * 128 + n];
        } else if (idx < 106496) {    // L2: K=128,N=64
            int l = idx - 98304;    int n = l >> 7;  int k = l & 127;
            v = w2[k * 64 + n];
        } else if (idx < 108544) {    // L3: K=64,N=32
            int l = idx - 106496;   int n = l >> 6;  int k = l & 63;
            v = w3[k * 32 + n];
        } else {                      // L4: K=32,N=32
            int l = idx - 108544;   int n = l >> 5;  int k = l & 31;
            v = w4[k * 32 + n];
        }
        wt[idx] = f2bf(v);
    } else if (idx < MLPW_CNT + WEFF_CNT) {
        int it = idx - MLPW_CNT;
        int n = it / 160, k = it - n * 160;
        float acc = 0.f;
        if (n < 300 && k < 147) {
            int oc = n % 12, p = n / 12, oy = p / 5, ox = p - oy * 5;
            int ci = k % 3,  t = k / 3, iy = t / 7, ix = t - iy * 7;
            for (int y = 0; y < 5; ++y) {
                int ky = iy - y + 1, ly = y - oy + 1;
                if ((unsigned)ky < 5u && (unsigned)ly < 3u) {
                    for (int x = 0; x < 5; ++x) {
                        int kx = ix - x + 1, lx = x - ox + 1;
                        if ((unsigned)kx < 5u && (unsigned)lx < 3u) {
                            const float* p1 = c1w + ((ky * 5 + kx) * 3 + ci) * 8;
                            const float* p2 = c2w + ((ly * 3 + lx) * 8) * 12 + oc;
#pragma unroll
                            for (int c = 0; c < 8; ++c) acc += p1[c] * p2[c * 12];
                        }
                    }
                }
            }
        }
        weff[it] = f2bf(acc);
    } else if (idx < MLPW_CNT + WEFF_CNT + 320) {
        int n = idx - MLPW_CNT - WEFF_CNT;
        float acc = 0.f;
        if (n < 300) {
            int oc = n % 12, p = n / 12, oy = p / 5, ox = p - oy * 5;
            acc = c2b[oc];
            for (int y = 0; y < 5; ++y) {
                int ly = y - oy + 1;
                if ((unsigned)ly < 3u) {
                    for (int x = 0; x < 5; ++x) {
                        int lx = x - ox + 1;
                        if ((unsigned)lx < 3u) {
#pragma unroll
                            for (int c = 0; c < 8; ++c)
                                acc += c2w[((ly * 3 + lx) * 8 + c) * 12 + oc] * c1b[c];
                        }
                    }
                }
            }
        }
        beff[n] = acc;
    }
}

// ---------------------------------------------------------------------------
// Kernel 1: fused 5-layer MLP via bf16 MFMA (unchanged from R4, proven).
// ---------------------------------------------------------------------------
template<int K, int N, bool RELU, bool LAST>
__device__ inline void layerW(const short* __restrict__ WT,
                              const float* __restrict__ bias,
                              const short* __restrict__ lIn,
                              short* __restrict__ lOut,
                              short* __restrict__ qout,
                              int wv, int lane, int r0)
{
    constexpr int KT  = K / 32;
    constexpr int NTW = (N >= 64) ? (N / 64) : 1;
    constexpr int MASKI = (K / 8 - 1) & 7;
    constexpr int MASKO = (N / 8 - 1) & 7;
    const int lanelo = lane & 15;
    const int g      = lane >> 4;
    const int nbase  = (N >= 64) ? wv * (N / 4) : wv * 16;
    if (N < 64 && wv >= 2) return;

    short8 af0[KT], af1[KT];
#pragma unroll
    for (int kt = 0; kt < KT; ++kt) {
        int phys = (kt * 4 + g) ^ (lanelo & MASKI);
        af0[kt] = *(const short8*)(lIn + lanelo * K + phys * 8);
        af1[kt] = *(const short8*)(lIn + (16 + lanelo) * K + phys * 8);
    }

    float bv[NTW];
#pragma unroll
    for (int nt = 0; nt < NTW; ++nt) bv[nt] = bias[nbase + nt * 16 + lanelo];

    short8 bf[2][KT];
    {
        const short* wb = WT + (nbase + lanelo) * K + g * 8;
#pragma unroll
        for (int kt = 0; kt < KT; ++kt) bf[0][kt] = *(const short8*)(wb + kt * 32);
    }

#pragma unroll
    for (int nt = 0; nt < NTW; ++nt) {
        if (nt + 1 < NTW) {
            const short* wb = WT + (nbase + (nt + 1) * 16 + lanelo) * K + g * 8;
#pragma unroll
            for (int kt = 0; kt < KT; ++kt)
                bf[(nt + 1) & 1][kt] = *(const short8*)(wb + kt * 32);
        }
        f32x4 a0, a1;
        a0[0] = 0.f; a0[1] = 0.f; a0[2] = 0.f; a0[3] = 0.f;
        a1[0] = 0.f; a1[1] = 0.f; a1[2] = 0.f; a1[3] = 0.f;
#pragma unroll
        for (int kt = 0; kt < KT; ++kt) {
            a0 = __builtin_amdgcn_mfma_f32_16x16x32_bf16(af0[kt], bf[nt & 1][kt], a0, 0, 0, 0);
            a1 = __builtin_amdgcn_mfma_f32_16x16x32_bf16(af1[kt], bf[nt & 1][kt], a1, 0, 0, 0);
        }
        const int n = nbase + nt * 16 + lanelo;
#pragma unroll
        for (int j = 0; j < 4; ++j) {
            int m0r = g * 4 + j, m1r = 16 + g * 4 + j;
            float v0 = a0[j] + bv[nt];
            float v1 = a1[j] + bv[nt];
            if (RELU) { v0 = fmaxf(v0, 0.f); v1 = fmaxf(v1, 0.f); }
            if (LAST) {
                qout[(r0 + m0r) * 32 + n] = f2bf(v0);
                qout[(r0 + m1r) * 32 + n] = f2bf(v1);
            } else {
                int p0 = ((n >> 3) ^ (m0r & MASKO));
                int p1 = ((n >> 3) ^ (m1r & MASKO));
                lOut[m0r * N + p0 * 8 + (n & 7)] = f2bf(v0);
                lOut[m1r * N + p1 * 8 + (n & 7)] = f2bf(v1);
            }
        }
    }
}

__global__ void __launch_bounds__(256) mlp_kernel(
    const float* __restrict__ hid,
    const float* __restrict__ qb0, const float* __restrict__ qb1,
    const float* __restrict__ qb2, const float* __restrict__ qb3,
    const float* __restrict__ qb4,
    const short* __restrict__ wsW,
    short* __restrict__ qout)
{
    __shared__ short lA[32 * 256];
    __shared__ short lB[32 * 256];
    const int tid  = threadIdx.x;
    const int wv   = tid >> 6;
    const int lane = tid & 63;
    const int r0   = blockIdx.x * 32;

#pragma unroll
    for (int i = 0; i < 4; ++i) {
        int cid = tid + 256 * i;
        int rrow = cid >> 5, ch = cid & 31;
        const float* src = hid + (r0 + rrow) * 256 + ch * 8;
        float4 v0 = reinterpret_cast<const float4*>(src)[0];
        float4 v1 = reinterpret_cast<const float4*>(src)[1];
        short8 s;
        s[0] = f2bf(v0.x); s[1] = f2bf(v0.y); s[2] = f2bf(v0.z); s[3] = f2bf(v0.w);
        s[4] = f2bf(v1.x); s[5] = f2bf(v1.y); s[6] = f2bf(v1.z); s[7] = f2bf(v1.w);
        int phys = ch ^ (rrow & 7);
        *(short8*)(lA + rrow * 256 + phys * 8) = s;
    }
    __syncthreads();

    layerW<256, 256, true,  false>(wsW,          qb0, lA, lB, nullptr, wv, lane, r0);
    __syncthreads();
    layerW<256, 128, true,  false>(wsW + 65536,  qb1, lB, lA, nullptr, wv, lane, r0);
    __syncthreads();
    layerW<128,  64, true,  false>(wsW + 98304,  qb2, lA, lB, nullptr, wv, lane, r0);
    __syncthreads();
    layerW< 64,  32, true,  false>(wsW + 106496, qb3, lB, lA, nullptr, wv, lane, r0);
    __syncthreads();
    layerW< 32,  32, false, true >(wsW + 108544, qb4, lA, nullptr, qout, wv, lane, r0);
}

// ---------------------------------------------------------------------------
// Kernel 2 v3: conv-as-GEMM + attention + head.
// Spatial basis is NOT materialized into K/V: logits use Kc(4ch)+sS dot,
// PV uses Vc(8ch)+sS.  LDS pool 31.9 KB -> 5 WG/CU.
// S1 uses all 256 threads (2 lanes per (el,qi), odd/even positions,
// combined with __shfl_xor(.,1)).
// LDS pool layout (31888 B):
//   [0)      sX [32][192] bf16 staging (12288) — reused after GEMM by:
//   [0)      sKc [32][25*4] bf16   (6400)
//   [6400)   sVc [32][25*8] bf16   (12800)
//   [19200)  sQ  [32][32]   bf16   (2048)
//   [21248)  sS  [100]      f32    (400)
//   [21648)  sA  [32][48]   f32    (6144)
//   [27792)  sH  [32][32]   f32    (4096)
// ---------------------------------------------------------------------------
__global__ void __launch_bounds__(256) conv_attn_kernel(
    const float* __restrict__ Xg,
    const short* __restrict__ weffT,
    const float* __restrict__ beff,
    const float* __restrict__ aw0, const float* __restrict__ ab0,
    const float* __restrict__ aw1, const float* __restrict__ ab1,
    const short* __restrict__ qb16,
    float* __restrict__ out)
{
    __shared__ __align__(16) unsigned char spool[31888];
    short* sX  = (short*)spool;
    short* sKc = (short*)spool;
    short* sVc = (short*)(spool + 6400);
    short* sQ  = (short*)(spool + 19200);
    float* sS  = (float*)(spool + 21248);
    float* sA  = (float*)(spool + 21648);
    float* sH  = (float*)(spool + 27792);

    const int tid    = threadIdx.x;
    const int wv     = tid >> 6;
    const int lane   = tid & 63;
    const int lanelo = lane & 15;
    const int g      = lane >> 4;
    const int blk    = blockIdx.x;

    // ---- phase G: stage X (bf16, swizzled, zero-padded to 160 cols) ----
#pragma unroll
    for (int it = 0; it < 20; ++it) {
        int idx = tid + it * 256;              // 5120 = 32 rows x 160 cols
        int row = idx / 160;
        int col = idx - row * 160;
        float v = (col < 147) ? Xg[blk * 4704 + row * 147 + col] : 0.f;
        int ch = col >> 3;
        sX[row * 192 + ((ch ^ (row & 7)) << 3) + (col & 7)] = f2bf(v);
    }
    {
        short4v qv = *(const short4v*)(qb16 + blk * 1024 + tid * 4);
        *(short4v*)(sQ + tid * 4) = qv;
    }
    if (tid < 100) {
        int p = tid >> 2, k = tid & 3;
        int h = p / 5, w = p - 5 * h;
        int u = (k >> 1) + 1, v = (k & 1) + 1;
        const float PI5 = 0.6283185307179586f;
        sS[tid] = cosf(((float)(h + 1) * PI5) * (float)u) *
                  cosf(((float)(w + 1) * PI5) * (float)v);
    }
    __syncthreads();

    // ---- GEMM: 2 m-tiles x 5 n-tiles x 5 k-tiles per wave ----
    short8 af[2][5];
#pragma unroll
    for (int m = 0; m < 2; ++m)
#pragma unroll
        for (int kt = 0; kt < 5; ++kt) {
            int row = m * 16 + lanelo;
            int phys = (kt * 4 + g) ^ (row & 7);
            af[m][kt] = *(const short8*)(sX + row * 192 + phys * 8);
        }

    f32x4 acc[2][5];
#pragma unroll
    for (int m = 0; m < 2; ++m)
#pragma unroll
        for (int nt = 0; nt < 5; ++nt) {
            acc[m][nt][0] = 0.f; acc[m][nt][1] = 0.f;
            acc[m][nt][2] = 0.f; acc[m][nt][3] = 0.f;
        }

    const short* wbase = weffT + (wv * 80 + lanelo) * 160 + g * 8;
#pragma unroll
    for (int nt = 0; nt < 5; ++nt) {
        const short* wn = wbase + nt * 16 * 160;
#pragma unroll
        for (int kt = 0; kt < 5; ++kt) {
            short8 bf = *(const short8*)(wn + kt * 32);
            acc[0][nt] = __builtin_amdgcn_mfma_f32_16x16x32_bf16(af[0][kt], bf, acc[0][nt], 0, 0, 0);
            acc[1][nt] = __builtin_amdgcn_mfma_f32_16x16x32_bf16(af[1][kt], bf, acc[1][nt], 0, 0, 0);
        }
    }
    float bv[5];
#pragma unroll
    for (int nt = 0; nt < 5; ++nt) bv[nt] = beff[wv * 80 + nt * 16 + lanelo];
    __syncthreads();   // all waves done reading sX; Kc/Vc region reuses it

    // ---- scatter O + bias into Kc (4ch) / Vc (8ch) ----
#pragma unroll
    for (int nt = 0; nt < 5; ++nt) {
        int n = wv * 80 + nt * 16 + lanelo;
        if (n < 300) {
            int p = n / 12, c = n - p * 12;
#pragma unroll
            for (int m = 0; m < 2; ++m)
#pragma unroll
                for (int j = 0; j < 4; ++j) {
                    int row = m * 16 + g * 4 + j;
                    float v = acc[m][nt][j] + bv[nt];
                    if (c < 4) sKc[row * 100 + p * 4 + c]       = f2bf(v);
                    else       sVc[row * 200 + p * 8 + (c - 4)] = f2bf(v);
                }
        }
    }
    __syncthreads();

    // ---- S1: logits -> softmax -> PV, all 256 threads ----
    // thread = (el, qi, hf): hf handles positions p = hf, hf+2, ...
    {
        const int el = tid >> 3, qi = (tid >> 1) & 3, hf = tid & 1;
        short8 qv = *(const short8*)(sQ + el * 32 + qi * 8);
        float qf[8];
#pragma unroll
        for (int i = 0; i < 8; ++i) qf[i] = b2f(qv[i]);

        float lg[13];
        float mx = -1e30f;
#pragma unroll
        for (int i = 0; i < 13; ++i) {
            int p = hf + 2 * i;
            if (p < 25) {
                short4v kv = *(const short4v*)(sKc + el * 100 + p * 4);
                const float* sp = sS + p * 4;
                float s = b2f(kv[0]) * qf[0] + b2f(kv[1]) * qf[1]
                        + b2f(kv[2]) * qf[2] + b2f(kv[3]) * qf[3]
                        + sp[0] * qf[4] + sp[1] * qf[5]
                        + sp[2] * qf[6] + sp[3] * qf[7];
                lg[i] = s;
                mx = fmaxf(mx, s);
            } else {
                lg[i] = -1e30f;
            }
        }
        mx = fmaxf(mx, __shfl_xor(mx, 1));
        float sum = 0.f;
#pragma unroll
        for (int i = 0; i < 13; ++i) { lg[i] = __expf(lg[i] - mx); sum += lg[i]; }
        sum += __shfl_xor(sum, 1);
        float inv = 1.f / sum;

        float o[12];
#pragma unroll
        for (int d = 0; d < 12; ++d) o[d] = 0.f;
#pragma unroll
        for (int i = 0; i < 13; ++i) {
            int p = hf + 2 * i;
            if (p < 25) {
                float w = lg[i];
                short4v v0 = *(const short4v*)(sVc + el * 200 + p * 8);
                short4v v1 = *(const short4v*)(sVc + el * 200 + p * 8 + 4);
                const float* sp = sS + p * 4;
                o[0] += w * b2f(v0[0]); o[1] += w * b2f(v0[1]);
                o[2] += w * b2f(v0[2]); o[3] += w * b2f(v0[3]);
                o[4] += w * b2f(v1[0]); o[5] += w * b2f(v1[1]);
                o[6] += w * b2f(v1[2]); o[7] += w * b2f(v1[3]);
                o[8]  += w * sp[0]; o[9]  += w * sp[1];
                o[10] += w * sp[2]; o[11] += w * sp[3];
            }
        }
#pragma unroll
        for (int d = 0; d < 12; ++d) {
            float t = o[d] + __shfl_xor(o[d], 1);
            o[d] = t * inv;
        }
        if (hf == 0) {
#pragma unroll
            for (int d = 0; d < 12; ++d) sA[el * 48 + qi * 12 + d] = o[d];
        }
    }
    __syncthreads();

    // ---- S2: h1 = relu(a @ aw0 + ab0) ----
    {
        int el = tid >> 3, t8 = tid & 7;
        float a4[4];
        float4 b0 = *(const float4*)(ab0 + t8 * 4);
        a4[0] = b0.x; a4[1] = b0.y; a4[2] = b0.z; a4[3] = b0.w;
#pragma unroll
        for (int i = 0; i < 48; ++i) {
            float av = sA[el * 48 + i];
            float4 wv4 = *(const float4*)(aw0 + i * 32 + t8 * 4);
            a4[0] += av * wv4.x; a4[1] += av * wv4.y;
            a4[2] += av * wv4.z; a4[3] += av * wv4.w;
        }
#pragma unroll
        for (int jj = 0; jj < 4; ++jj)
            sH[el * 32 + t8 * 4 + jj] = fmaxf(a4[jj], 0.f);
    }
    __syncthreads();

    // ---- S3: out = h1 @ aw1 + ab1 ----
    {
        int el = tid >> 3, t8 = tid & 7;
        float a8[8];
        float4 b0 = *(const float4*)(ab1 + t8 * 8);
        float4 b1 = *(const float4*)(ab1 + t8 * 8 + 4);
        a8[0] = b0.x; a8[1] = b0.y; a8[2] = b0.z; a8[3] = b0.w;
        a8[4] = b1.x; a8[5] = b1.y; a8[6] = b1.z; a8[7] = b1.w;
#pragma unroll
        for (int j = 0; j < 32; ++j) {
            float hv = sH[el * 32 + j];
            float4 w0v = *(const float4*)(aw1 + j * 64 + t8 * 8);
            float4 w1v = *(const float4*)(aw1 + j * 64 + t8 * 8 + 4);
            a8[0] += hv * w0v.x; a8[1] += hv * w0v.y;
            a8[2] += hv * w0v.z; a8[3] += hv * w0v.w;
            a8[4] += hv * w1v.x; a8[5] += hv * w1v.y;
            a8[6] += hv * w1v.z; a8[7] += hv * w1v.w;
        }
        int e = blk * 32 + el;
        float4 o0; o0.x = a8[0]; o0.y = a8[1]; o0.z = a8[2]; o0.w = a8[3];
        float4 o1; o1.x = a8[4]; o1.y = a8[5]; o1.z = a8[6]; o1.w = a8[7];
        *(float4*)(out + e * 64 + t8 * 8)     = o0;
        *(float4*)(out + e * 64 + t8 * 8 + 4) = o1;
    }
}

// ---------------------------------------------------------------------------

extern "C" void kernel_launch(void* const* d_in, const int* in_sizes, int n_in,
                              void* d_out, int out_size, void* d_ws, size_t ws_size,
                              hipStream_t stream)
{
    const float* X   = (const float*)d_in[0];
    const float* hid = (const float*)d_in[1];
    const float* c1w = (const float*)d_in[2];
    const float* c1b = (const float*)d_in[3];
    const float* c2w = (const float*)d_in[4];
    const float* c2b = (const float*)d_in[5];
    const float* qw0 = (const float*)d_in[6];
    const float* qb0 = (const float*)d_in[7];
    const float* qw1 = (const float*)d_in[8];
    const float* qb1 = (const float*)d_in[9];
    const float* qw2 = (const float*)d_in[10];
    const float* qb2 = (const float*)d_in[11];
    const float* qw3 = (const float*)d_in[12];
    const float* qb3 = (const float*)d_in[13];
    const float* qw4 = (const float*)d_in[14];
    const float* qb4 = (const float*)d_in[15];
    const float* aw0 = (const float*)d_in[16];
    const float* ab0 = (const float*)d_in[17];
    const float* aw1 = (const float*)d_in[18];
    const float* ab1 = (const float*)d_in[19];

    float* out   = (float*)d_out;
    short* qb16  = (short*)d_ws;
    short* wsW   = qb16 + (size_t)NB * 32;
    short* weffT = wsW + MLPW_CNT;
    float* beff  = (float*)(weffT + WEFF_CNT);

    hipLaunchKernelGGL(prep_kernel, dim3(630), dim3(256), 0, stream,
                       qw0, qw1, qw2, qw3, qw4, c1w, c1b, c2w, c2b,
                       wsW, weffT, beff);
    hipLaunchKernelGGL(mlp_kernel, dim3(NB / 32), dim3(256), 0, stream,
                       hid, qb0, qb1, qb2, qb3, qb4, wsW, qb16);
    hipLaunchKernelGGL(conv_attn_kernel, dim3(NB / 32), dim3(256), 0, stream,
                       X, weffT, beff, aw0, ab0, aw1, ab1, qb16, out);
}

// Round 6
// 109.917 us; speedup vs baseline: 6.8495x; 1.3468x over previous
//
#include <hip/hip_runtime.h>
#include <hip/hip_bf16.h>

#define NB 65536

typedef __attribute__((ext_vector_type(8))) short short8;
typedef __attribute__((ext_vector_type(4))) short short4v;
typedef __attribute__((ext_vector_type(4))) float f32x4;

__device__ inline short f2bf(float f) {
    unsigned u = __builtin_bit_cast(unsigned, f);
    unsigned r = (u + 0x7fffu + ((u >> 16) & 1u)) >> 16;   // RNE
    return (short)(unsigned short)r;
}
__device__ inline float b2f(short s) {
    return __builtin_bit_cast(float, (unsigned)((unsigned short)s) << 16);
}

#define MLPW_CNT 109568
#define WEFF_CNT 51200
// prep index-space extents
#define A0 (MLPW_CNT + WEFF_CNT + 320)   // aw0T start
#define A1 (A0 + 2048)                   // aw1T start
#define A2 (A1 + 2048)                   // sTab start
#define PREP_TOT (A2 + 100)

// ---------------------------------------------------------------------------
// Kernel 0: prep — MLP weights^T bf16; composed conv Weff^T bf16 [320][160];
// beff f32[320]; aw0T bf16 [32][64] (K 48->64 zero-pad); aw1T bf16 [64][32];
// spatial-basis table sTab f32[100].
// ---------------------------------------------------------------------------
__global__ void __launch_bounds__(256) prep_kernel(
    const float* __restrict__ w0, const float* __restrict__ w1,
    const float* __restrict__ w2, const float* __restrict__ w3,
    const float* __restrict__ w4,
    const float* __restrict__ c1w, const float* __restrict__ c1b,
    const float* __restrict__ c2w, const float* __restrict__ c2b,
    const float* __restrict__ aw0, const float* __restrict__ aw1,
    short* __restrict__ wt, short* __restrict__ weff, float* __restrict__ beff,
    short* __restrict__ aw0T, short* __restrict__ aw1T, float* __restrict__ sTab)
{
    int idx = blockIdx.x * 256 + threadIdx.x;
    if (idx < MLPW_CNT) {
        float v;
        if (idx < 65536) {            // L0: K=256,N=256
            int l = idx;            int n = l >> 8;  int k = l & 255;
            v = w0[k * 256 + n];
        } else if (idx < 98304) {     // L1: K=256,N=128
            int l = idx - 65536;    int n = l >> 8;  int k = l & 255;
            v = w1[k * 128 + n];
        } else if (idx < 106496) {    // L2: K=128,N=64
            int l = idx - 98304;    int n = l >> 7;  int k = l & 127;
            v = w2[k * 64 + n];
        } else if (idx < 108544) {    // L3: K=64,N=32
            int l = idx - 106496;   int n = l >> 6;  int k = l & 63;
            v = w3[k * 32 + n];
        } else {                      // L4: K=32,N=32
            int l = idx - 108544;   int n = l >> 5;  int k = l & 31;
            v = w4[k * 32 + n];
        }
        wt[idx] = f2bf(v);
    } else if (idx < MLPW_CNT + WEFF_CNT) {
        int it = idx - MLPW_CNT;
        int n = it / 160, k = it - n * 160;
        float acc = 0.f;
        if (n < 300 && k < 147) {
            int oc = n % 12, p = n / 12, oy = p / 5, ox = p - oy * 5;
            int ci = k % 3,  t = k / 3, iy = t / 7, ix = t - iy * 7;
            for (int y = 0; y < 5; ++y) {
                int ky = iy - y + 1, ly = y - oy + 1;
                if ((unsigned)ky < 5u && (unsigned)ly < 3u) {
                    for (int x = 0; x < 5; ++x) {
                        int kx = ix - x + 1, lx = x - ox + 1;
                        if ((unsigned)kx < 5u && (unsigned)lx < 3u) {
                            const float* p1 = c1w + ((ky * 5 + kx) * 3 + ci) * 8;
                            const float* p2 = c2w + ((ly * 3 + lx) * 8) * 12 + oc;
#pragma unroll
                            for (int c = 0; c < 8; ++c) acc += p1[c] * p2[c * 12];
                        }
                    }
                }
            }
        }
        weff[it] = f2bf(acc);
    } else if (idx < A0) {
        int n = idx - MLPW_CNT - WEFF_CNT;
        float acc = 0.f;
        if (n < 300) {
            int oc = n % 12, p = n / 12, oy = p / 5, ox = p - oy * 5;
            acc = c2b[oc];
            for (int y = 0; y < 5; ++y) {
                int ly = y - oy + 1;
                if ((unsigned)ly < 3u) {
                    for (int x = 0; x < 5; ++x) {
                        int lx = x - ox + 1;
                        if ((unsigned)lx < 3u) {
#pragma unroll
                            for (int c = 0; c < 8; ++c)
                                acc += c2w[((ly * 3 + lx) * 8 + c) * 12 + oc] * c1b[c];
                        }
                    }
                }
            }
        }
        beff[n] = acc;
    } else if (idx < A1) {
        int t = idx - A0;
        int n = t >> 6, k = t & 63;           // [32][64]
        aw0T[t] = (k < 48) ? f2bf(aw0[k * 32 + n]) : (short)0;
    } else if (idx < A2) {
        int t = idx - A1;
        int n = t >> 5, k = t & 31;           // [64][32]
        aw1T[t] = f2bf(aw1[k * 64 + n]);
    } else if (idx < PREP_TOT) {
        int i = idx - A2;
        int p = i >> 2, s = i & 3;
        int h = p / 5, w = p - 5 * h;
        int u = (s >> 1) + 1, v = (s & 1) + 1;
        const float PI5 = 0.6283185307179586f;
        sTab[i] = cosf(((float)(h + 1) * PI5) * (float)u) *
                  cosf(((float)(w + 1) * PI5) * (float)v);
    }
}

// ---------------------------------------------------------------------------
// Kernel 1: fused 5-layer MLP via bf16 MFMA (unchanged from R4, proven).
// ---------------------------------------------------------------------------
template<int K, int N, bool RELU, bool LAST>
__device__ inline void layerW(const short* __restrict__ WT,
                              const float* __restrict__ bias,
                              const short* __restrict__ lIn,
                              short* __restrict__ lOut,
                              short* __restrict__ qout,
                              int wv, int lane, int r0)
{
    constexpr int KT  = K / 32;
    constexpr int NTW = (N >= 64) ? (N / 64) : 1;
    constexpr int MASKI = (K / 8 - 1) & 7;
    constexpr int MASKO = (N / 8 - 1) & 7;
    const int lanelo = lane & 15;
    const int g      = lane >> 4;
    const int nbase  = (N >= 64) ? wv * (N / 4) : wv * 16;
    if (N < 64 && wv >= 2) return;

    short8 af0[KT], af1[KT];
#pragma unroll
    for (int kt = 0; kt < KT; ++kt) {
        int phys = (kt * 4 + g) ^ (lanelo & MASKI);
        af0[kt] = *(const short8*)(lIn + lanelo * K + phys * 8);
        af1[kt] = *(const short8*)(lIn + (16 + lanelo) * K + phys * 8);
    }

    float bv[NTW];
#pragma unroll
    for (int nt = 0; nt < NTW; ++nt) bv[nt] = bias[nbase + nt * 16 + lanelo];

    short8 bf[2][KT];
    {
        const short* wb = WT + (nbase + lanelo) * K + g * 8;
#pragma unroll
        for (int kt = 0; kt < KT; ++kt) bf[0][kt] = *(const short8*)(wb + kt * 32);
    }

#pragma unroll
    for (int nt = 0; nt < NTW; ++nt) {
        if (nt + 1 < NTW) {
            const short* wb = WT + (nbase + (nt + 1) * 16 + lanelo) * K + g * 8;
#pragma unroll
            for (int kt = 0; kt < KT; ++kt)
                bf[(nt + 1) & 1][kt] = *(const short8*)(wb + kt * 32);
        }
        f32x4 a0, a1;
        a0[0] = 0.f; a0[1] = 0.f; a0[2] = 0.f; a0[3] = 0.f;
        a1[0] = 0.f; a1[1] = 0.f; a1[2] = 0.f; a1[3] = 0.f;
#pragma unroll
        for (int kt = 0; kt < KT; ++kt) {
            a0 = __builtin_amdgcn_mfma_f32_16x16x32_bf16(af0[kt], bf[nt & 1][kt], a0, 0, 0, 0);
            a1 = __builtin_amdgcn_mfma_f32_16x16x32_bf16(af1[kt], bf[nt & 1][kt], a1, 0, 0, 0);
        }
        const int n = nbase + nt * 16 + lanelo;
#pragma unroll
        for (int j = 0; j < 4; ++j) {
            int m0r = g * 4 + j, m1r = 16 + g * 4 + j;
            float v0 = a0[j] + bv[nt];
            float v1 = a1[j] + bv[nt];
            if (RELU) { v0 = fmaxf(v0, 0.f); v1 = fmaxf(v1, 0.f); }
            if (LAST) {
                qout[(r0 + m0r) * 32 + n] = f2bf(v0);
                qout[(r0 + m1r) * 32 + n] = f2bf(v1);
            } else {
                int p0 = ((n >> 3) ^ (m0r & MASKO));
                int p1 = ((n >> 3) ^ (m1r & MASKO));
                lOut[m0r * N + p0 * 8 + (n & 7)] = f2bf(v0);
                lOut[m1r * N + p1 * 8 + (n & 7)] = f2bf(v1);
            }
        }
    }
}

__global__ void __launch_bounds__(256) mlp_kernel(
    const float* __restrict__ hid,
    const float* __restrict__ qb0, const float* __restrict__ qb1,
    const float* __restrict__ qb2, const float* __restrict__ qb3,
    const float* __restrict__ qb4,
    const short* __restrict__ wsW,
    short* __restrict__ qout)
{
    __shared__ short lA[32 * 256];
    __shared__ short lB[32 * 256];
    const int tid  = threadIdx.x;
    const int wv   = tid >> 6;
    const int lane = tid & 63;
    const int r0   = blockIdx.x * 32;

#pragma unroll
    for (int i = 0; i < 4; ++i) {
        int cid = tid + 256 * i;
        int rrow = cid >> 5, ch = cid & 31;
        const float* src = hid + (r0 + rrow) * 256 + ch * 8;
        float4 v0 = reinterpret_cast<const float4*>(src)[0];
        float4 v1 = reinterpret_cast<const float4*>(src)[1];
        short8 s;
        s[0] = f2bf(v0.x); s[1] = f2bf(v0.y); s[2] = f2bf(v0.z); s[3] = f2bf(v0.w);
        s[4] = f2bf(v1.x); s[5] = f2bf(v1.y); s[6] = f2bf(v1.z); s[7] = f2bf(v1.w);
        int phys = ch ^ (rrow & 7);
        *(short8*)(lA + rrow * 256 + phys * 8) = s;
    }
    __syncthreads();

    layerW<256, 256, true,  false>(wsW,          qb0, lA, lB, nullptr, wv, lane, r0);
    __syncthreads();
    layerW<256, 128, true,  false>(wsW + 65536,  qb1, lB, lA, nullptr, wv, lane, r0);
    __syncthreads();
    layerW<128,  64, true,  false>(wsW + 98304,  qb2, lA, lB, nullptr, wv, lane, r0);
    __syncthreads();
    layerW< 64,  32, true,  false>(wsW + 106496, qb3, lB, lA, nullptr, wv, lane, r0);
    __syncthreads();
    layerW< 32,  32, false, true >(wsW + 108544, qb4, lA, nullptr, qout, wv, lane, r0);
}

// ---------------------------------------------------------------------------
// Kernel 2 v4: SINGLE-WAVE workgroups, 16 elements per wave, no barriers.
// Per wave: stage X -> LDS (swz bf16) -> MFMA conv GEMM (1 m-tile x 19 nt x
// 5 kt, B double-buffered from L2) -> scatter Kc/Vc -> scalar attention
// (64 lanes = 16 el x 4 qi, serial 25 positions) -> MFMA head (S2: K48->64,
// S3: K32) -> coalesced out.
// LDS pool 14096 B (~11 WG/CU):
//   sKc [16][100]bf16 @0       sVc [16][200]bf16 @3200
//   sX  [16][192]bf16 @0 (overlaps; dead before scatter)
//   sQ  [16][32]bf16  @9600    sS [100]f32 @10624
//   sA  [16][64]bf16  @11024 (chunk-XOR swz)   sH [16][32]bf16 @13072 (swz)
// ---------------------------------------------------------------------------
__global__ void __launch_bounds__(64) conv_attn_kernel(
    const float* __restrict__ Xg,
    const short* __restrict__ weffT,
    const float* __restrict__ beff,
    const short* __restrict__ aw0T, const float* __restrict__ ab0,
    const short* __restrict__ aw1T, const float* __restrict__ ab1,
    const float* __restrict__ sTab,
    const short* __restrict__ qb16,
    float* __restrict__ out)
{
    __shared__ __align__(16) unsigned char spool[14096];
    short* sKc = (short*)spool;
    short* sVc = (short*)(spool + 3200);
    short* sX  = (short*)spool;
    short* sQ  = (short*)(spool + 9600);
    float* sS  = (float*)(spool + 10624);
    short* sA  = (short*)(spool + 11024);
    short* sH  = (short*)(spool + 13072);

    const int lane   = threadIdx.x;
    const int lanelo = lane & 15;
    const int g      = lane >> 4;
    const int blk    = blockIdx.x;

    // ---- stage q (16x32 bf16, 1 short8 per lane) ----
    {
        short8 qv = *(const short8*)(qb16 + blk * 512 + lane * 8);
        *(short8*)(sQ + lane * 8) = qv;
    }
    // ---- stage spatial table (100 f32) ----
    if (lane < 50) {
        float2 t = *(const float2*)(sTab + lane * 2);
        sS[lane * 2]     = t.x;
        sS[lane * 2 + 1] = t.y;
    }
    // ---- zero-pad X cols 147..159 (16 rows x 13 cols) ----
#pragma unroll
    for (int i = 0; i < 4; ++i) {
        int t = lane + i * 64;
        if (t < 208) {
            int r = t / 13, c = 147 + (t - r * 13);
            int ch = c >> 3;
            sX[r * 192 + ((ch ^ (r & 7)) << 3) + (c & 7)] = 0;
        }
    }
    // ---- stage X: 588 float4, scatter w/ swizzle ----
    {
        const float* xb = Xg + (size_t)blk * 2352;
#define PUTX(IDX, F) { int _i = (IDX); int _r = _i / 147; int _c = _i - _r * 147; \
        int _ch = _c >> 3; sX[_r * 192 + ((_ch ^ (_r & 7)) << 3) + (_c & 7)] = f2bf(F); }
#pragma unroll
        for (int i = 0; i < 10; ++i) {
            int idx4 = lane + i * 64;
            if (idx4 < 588) {
                float4 v = reinterpret_cast<const float4*>(xb)[idx4];
                int base = idx4 * 4;
                PUTX(base + 0, v.x)
                PUTX(base + 1, v.y)
                PUTX(base + 2, v.z)
                PUTX(base + 3, v.w)
            }
        }
#undef PUTX
    }

    // ---- A-fragments (sX dead after this) ----
    short8 af[5];
#pragma unroll
    for (int kt = 0; kt < 5; ++kt) {
        int phys = (kt * 4 + g) ^ (lanelo & 7);
        af[kt] = *(const short8*)(sX + lanelo * 192 + phys * 8);
    }

    // ---- conv GEMM: 19 n-tiles x 5 k-tiles, B dbuf, scatter per nt ----
    short8 bf[2][5];
    {
        const short* wb = weffT + lanelo * 160 + g * 8;
#pragma unroll
        for (int kt = 0; kt < 5; ++kt) bf[0][kt] = *(const short8*)(wb + kt * 32);
    }
#pragma unroll
    for (int nt = 0; nt < 19; ++nt) {
        if (nt + 1 < 19) {
            const short* wb = weffT + ((nt + 1) * 16 + lanelo) * 160 + g * 8;
#pragma unroll
            for (int kt = 0; kt < 5; ++kt)
                bf[(nt + 1) & 1][kt] = *(const short8*)(wb + kt * 32);
        }
        f32x4 a; a[0] = 0.f; a[1] = 0.f; a[2] = 0.f; a[3] = 0.f;
#pragma unroll
        for (int kt = 0; kt < 5; ++kt)
            a = __builtin_amdgcn_mfma_f32_16x16x32_bf16(af[kt], bf[nt & 1][kt], a, 0, 0, 0);
        int n = nt * 16 + lanelo;
        if (n < 300) {
            float bb = beff[n];
            int p = n / 12, c = n - p * 12;
#pragma unroll
            for (int j = 0; j < 4; ++j) {
                int el = g * 4 + j;
                float v = a[j] + bb;
                if (c < 4) sKc[el * 100 + p * 4 + c]       = f2bf(v);
                else       sVc[el * 200 + p * 8 + (c - 4)] = f2bf(v);
            }
        }
    }

    // ---- S1: attention, lane = (el, qi), serial over 25 positions ----
    {
        const int el = lane >> 2, qi = lane & 3;
        short8 qv = *(const short8*)(sQ + el * 32 + qi * 8);
        float qf[8];
#pragma unroll
        for (int i = 0; i < 8; ++i) qf[i] = b2f(qv[i]);

        float lg[25];
        float mx = -1e30f;
#pragma unroll
        for (int p = 0; p < 25; ++p) {
            short4v kv = *(const short4v*)(sKc + el * 100 + p * 4);
            const float* sp = sS + p * 4;
            float s = b2f(kv[0]) * qf[0] + b2f(kv[1]) * qf[1]
                    + b2f(kv[2]) * qf[2] + b2f(kv[3]) * qf[3]
                    + sp[0] * qf[4] + sp[1] * qf[5]
                    + sp[2] * qf[6] + sp[3] * qf[7];
            lg[p] = s;
            mx = fmaxf(mx, s);
        }
        float sum = 0.f;
#pragma unroll
        for (int p = 0; p < 25; ++p) { lg[p] = __expf(lg[p] - mx); sum += lg[p]; }
        float inv = 1.f / sum;

        float o[12];
#pragma unroll
        for (int d = 0; d < 12; ++d) o[d] = 0.f;
#pragma unroll
        for (int p = 0; p < 25; ++p) {
            float w = lg[p];
            short4v v0 = *(const short4v*)(sVc + el * 200 + p * 8);
            short4v v1 = *(const short4v*)(sVc + el * 200 + p * 8 + 4);
            const float* sp = sS + p * 4;
            o[0] += w * b2f(v0[0]); o[1] += w * b2f(v0[1]);
            o[2] += w * b2f(v0[2]); o[3] += w * b2f(v0[3]);
            o[4] += w * b2f(v1[0]); o[5] += w * b2f(v1[1]);
            o[6] += w * b2f(v1[2]); o[7] += w * b2f(v1[3]);
            o[8]  += w * sp[0]; o[9]  += w * sp[1];
            o[10] += w * sp[2]; o[11] += w * sp[3];
        }
        // write a -> sA bf16 [16][64], chunk-XOR swizzle (chunk = col>>3)
#pragma unroll
        for (int d = 0; d < 12; ++d) {
            int col = qi * 12 + d;
            int ch = col >> 3;
            sA[el * 64 + ((ch ^ (el & 7)) << 3) + (col & 7)] = f2bf(o[d] * inv);
        }
        // zero-pad cols 48..63 (each lane does 4)
#pragma unroll
        for (int t = 0; t < 4; ++t) {
            int col = 48 + qi * 4 + t;
            int ch = col >> 3;
            sA[el * 64 + ((ch ^ (el & 7)) << 3) + (col & 7)] = 0;
        }
    }

    // ---- S2: h1 = relu(a @ aw0 + ab0) via MFMA (M=16,K=64,N=32) ----
    {
        short8 aa0, aa1;
        {
            int p0 = (0 * 4 + g) ^ (lanelo & 7);
            int p1 = (1 * 4 + g) ^ (lanelo & 7);
            aa0 = *(const short8*)(sA + lanelo * 64 + p0 * 8);
            aa1 = *(const short8*)(sA + lanelo * 64 + p1 * 8);
        }
#pragma unroll
        for (int nt2 = 0; nt2 < 2; ++nt2) {
            int n = nt2 * 16 + lanelo;
            short8 bw0 = *(const short8*)(aw0T + n * 64 + g * 8);
            short8 bw1 = *(const short8*)(aw0T + n * 64 + 32 + g * 8);
            f32x4 h; h[0] = 0.f; h[1] = 0.f; h[2] = 0.f; h[3] = 0.f;
            h = __builtin_amdgcn_mfma_f32_16x16x32_bf16(aa0, bw0, h, 0, 0, 0);
            h = __builtin_amdgcn_mfma_f32_16x16x32_bf16(aa1, bw1, h, 0, 0, 0);
            float bb = ab0[n];
#pragma unroll
            for (int j = 0; j < 4; ++j) {
                int row = g * 4 + j;
                int ch = n >> 3;
                float v = fmaxf(h[j] + bb, 0.f);
                sH[row * 32 + ((ch ^ (row & 3)) << 3) + (n & 7)] = f2bf(v);
            }
        }
    }

    // ---- S3: out = h1 @ aw1 + ab1 via MFMA (M=16,K=32,N=64) ----
    {
        short8 ah;
        {
            int ph = (g ^ (lanelo & 3));
            ah = *(const short8*)(sH + lanelo * 32 + ph * 8);
        }
#pragma unroll
        for (int nt3 = 0; nt3 < 4; ++nt3) {
            int n = nt3 * 16 + lanelo;
            short8 bw = *(const short8*)(aw1T + n * 32 + g * 8);
            f32x4 oacc; oacc[0] = 0.f; oacc[1] = 0.f; oacc[2] = 0.f; oacc[3] = 0.f;
            oacc = __builtin_amdgcn_mfma_f32_16x16x32_bf16(ah, bw, oacc, 0, 0, 0);
            float bb = ab1[n];
#pragma unroll
            for (int j = 0; j < 4; ++j) {
                int el = g * 4 + j;
                out[((size_t)blk * 16 + el) * 64 + n] = oacc[j] + bb;
            }
        }
    }
}

// ---------------------------------------------------------------------------

extern "C" void kernel_launch(void* const* d_in, const int* in_sizes, int n_in,
                              void* d_out, int out_size, void* d_ws, size_t ws_size,
                              hipStream_t stream)
{
    const float* X   = (const float*)d_in[0];
    const float* hid = (const float*)d_in[1];
    const float* c1w = (const float*)d_in[2];
    const float* c1b = (const float*)d_in[3];
    const float* c2w = (const float*)d_in[4];
    const float* c2b = (const float*)d_in[5];
    const float* qw0 = (const float*)d_in[6];
    const float* qb0 = (const float*)d_in[7];
    const float* qw1 = (const float*)d_in[8];
    const float* qb1 = (const float*)d_in[9];
    const float* qw2 = (const float*)d_in[10];
    const float* qb2 = (const float*)d_in[11];
    const float* qw3 = (const float*)d_in[12];
    const float* qb3 = (const float*)d_in[13];
    const float* qw4 = (const float*)d_in[14];
    const float* qb4 = (const float*)d_in[15];
    const float* aw0 = (const float*)d_in[16];
    const float* ab0 = (const float*)d_in[17];
    const float* aw1 = (const float*)d_in[18];
    const float* ab1 = (const float*)d_in[19];

    float* out   = (float*)d_out;
    short* qb16  = (short*)d_ws;
    short* wsW   = qb16 + (size_t)NB * 32;
    short* weffT = wsW + MLPW_CNT;
    float* beff  = (float*)(weffT + WEFF_CNT);
    short* aw0T  = (short*)(beff + 320);
    short* aw1T  = aw0T + 2048;
    float* sTab  = (float*)(aw1T + 2048);

    hipLaunchKernelGGL(prep_kernel, dim3((PREP_TOT + 255) / 256), dim3(256), 0, stream,
                       qw0, qw1, qw2, qw3, qw4, c1w, c1b, c2w, c2b, aw0, aw1,
                       wsW, weffT, beff, aw0T, aw1T, sTab);
    hipLaunchKernelGGL(mlp_kernel, dim3(NB / 32), dim3(256), 0, stream,
                       hid, qb0, qb1, qb2, qb3, qb4, wsW, qb16);
    hipLaunchKernelGGL(conv_attn_kernel, dim3(NB / 16), dim3(64), 0, stream,
                       X, weffT, beff, aw0T, ab0, aw1T, ab1, sTab, qb16, out);
}

// Round 7
// 89.473 us; speedup vs baseline: 8.4145x; 1.2285x over previous
//
#include <hip/hip_runtime.h>
#include <hip/hip_bf16.h>

#define NB 65536

typedef __attribute__((ext_vector_type(8))) short short8;
typedef __attribute__((ext_vector_type(4))) short short4v;
typedef __attribute__((ext_vector_type(4))) float f32x4;
typedef __attribute__((ext_vector_type(16))) float f32x16;
typedef __attribute__((ext_vector_type(4))) unsigned int u32x4;

__device__ inline short f2bf(float f) {
    unsigned u = __builtin_bit_cast(unsigned, f);
    unsigned r = (u + 0x7fffu + ((u >> 16) & 1u)) >> 16;   // RNE
    return (short)(unsigned short)r;
}
__device__ inline float b2f(short s) {
    return __builtin_bit_cast(float, (unsigned)((unsigned short)s) << 16);
}
__device__ inline unsigned pkbf(float lo, float hi) {
    return ((unsigned)(unsigned short)f2bf(hi) << 16) | (unsigned)(unsigned short)f2bf(lo);
}

#define MLPW_CNT 109568
#define WEFF_CNT 51200
// prep index-space extents
#define A0 (MLPW_CNT + WEFF_CNT + 320)   // aw0T start
#define A1 (A0 + 2048)                   // aw1T start
#define A2 (A1 + 2048)                   // sTab start
#define A3 (A2 + 100)                    // biasP start (512 f32)
#define PREP_TOT (A3 + 512)

// MLP weight layout (per layer): [NT][KT][64 lanes][8] bf16, where the frag
// for (nt,kt) is the 32x32x16 A-operand of W^T: n = nt*32+(lane&31),
// k = kt*16 + (lane>>5)*8 + j.  biasP (per layer): [2][N/2] f32 in D-layout:
// biasP[h][nt*16+r] = bias[nt*32 + (r&3) + 8*(r>>2) + 4*h].

// ---------------------------------------------------------------------------
// Kernel 0: prep
// ---------------------------------------------------------------------------
__global__ void __launch_bounds__(256) prep_kernel(
    const float* __restrict__ w0, const float* __restrict__ w1,
    const float* __restrict__ w2, const float* __restrict__ w3,
    const float* __restrict__ w4,
    const float* __restrict__ b0, const float* __restrict__ b1,
    const float* __restrict__ b2, const float* __restrict__ b3,
    const float* __restrict__ b4,
    const float* __restrict__ c1w, const float* __restrict__ c1b,
    const float* __restrict__ c2w, const float* __restrict__ c2b,
    const float* __restrict__ aw0, const float* __restrict__ aw1,
    short* __restrict__ wt, short* __restrict__ weff, float* __restrict__ beff,
    short* __restrict__ aw0T, short* __restrict__ aw1T, float* __restrict__ sTab,
    float* __restrict__ biasP)
{
    int idx = blockIdx.x * 256 + threadIdx.x;
    if (idx < MLPW_CNT) {
        // locate layer
        const float* W; int N, KT, base;
        if (idx < 65536)       { W = w0; N = 256; KT = 16; base = 0; }
        else if (idx < 98304)  { W = w1; N = 128; KT = 16; base = 65536; }
        else if (idx < 106496) { W = w2; N = 64;  KT = 8;  base = 98304; }
        else if (idx < 108544) { W = w3; N = 32;  KT = 4;  base = 106496; }
        else                   { W = w4; N = 32;  KT = 2;  base = 108544; }
        int i  = idx - base;
        int nt = i / (KT * 512);
        int r1 = i - nt * (KT * 512);
        int kt = r1 >> 9;
        int l  = (r1 & 511) >> 3;
        int j  = i & 7;
        int n  = nt * 32 + (l & 31);
        int k  = kt * 16 + ((l >> 5) << 3) + j;
        wt[idx] = f2bf(W[k * N + n]);
    } else if (idx < MLPW_CNT + WEFF_CNT) {
        int it = idx - MLPW_CNT;
        int n = it / 160, k = it - n * 160;
        float acc = 0.f;
        if (n < 300 && k < 147) {
            int oc = n % 12, p = n / 12, oy = p / 5, ox = p - oy * 5;
            int ci = k % 3,  t = k / 3, iy = t / 7, ix = t - iy * 7;
            for (int y = 0; y < 5; ++y) {
                int ky = iy - y + 1, ly = y - oy + 1;
                if ((unsigned)ky < 5u && (unsigned)ly < 3u) {
                    for (int x = 0; x < 5; ++x) {
                        int kx = ix - x + 1, lx = x - ox + 1;
                        if ((unsigned)kx < 5u && (unsigned)lx < 3u) {
                            const float* p1 = c1w + ((ky * 5 + kx) * 3 + ci) * 8;
                            const float* p2 = c2w + ((ly * 3 + lx) * 8) * 12 + oc;
#pragma unroll
                            for (int c = 0; c < 8; ++c) acc += p1[c] * p2[c * 12];
                        }
                    }
                }
            }
        }
        weff[it] = f2bf(acc);
    } else if (idx < A0) {
        int n = idx - MLPW_CNT - WEFF_CNT;
        float acc = 0.f;
        if (n < 300) {
            int oc = n % 12, p = n / 12, oy = p / 5, ox = p - oy * 5;
            acc = c2b[oc];
            for (int y = 0; y < 5; ++y) {
                int ly = y - oy + 1;
                if ((unsigned)ly < 3u) {
                    for (int x = 0; x < 5; ++x) {
                        int lx = x - ox + 1;
                        if ((unsigned)lx < 3u) {
#pragma unroll
                            for (int c = 0; c < 8; ++c)
                                acc += c2w[((ly * 3 + lx) * 8 + c) * 12 + oc] * c1b[c];
                        }
                    }
                }
            }
        }
        beff[n] = acc;
    } else if (idx < A1) {
        int t = idx - A0;
        int n = t >> 6, k = t & 63;           // [32][64]
        aw0T[t] = (k < 48) ? f2bf(aw0[k * 32 + n]) : (short)0;
    } else if (idx < A2) {
        int t = idx - A1;
        int n = t >> 5, k = t & 31;           // [64][32]
        aw1T[t] = f2bf(aw1[k * 64 + n]);
    } else if (idx < A3) {
        int i = idx - A2;
        int p = i >> 2, s = i & 3;
        int h = p / 5, w = p - 5 * h;
        int u = (s >> 1) + 1, v = (s & 1) + 1;
        const float PI5 = 0.6283185307179586f;
        sTab[i] = cosf(((float)(h + 1) * PI5) * (float)u) *
                  cosf(((float)(w + 1) * PI5) * (float)v);
    } else if (idx < PREP_TOT) {
        int t = idx - A3;
        const float* B; int N, base;
        if (t < 256)      { B = b0; N = 256; base = 0; }
        else if (t < 384) { B = b1; N = 128; base = 256; }
        else if (t < 448) { B = b2; N = 64;  base = 384; }
        else if (t < 480) { B = b3; N = 32;  base = 448; }
        else              { B = b4; N = 32;  base = 480; }
        int u  = t - base;
        int h  = u / (N / 2);
        int w  = u - h * (N / 2);
        int nt = w >> 4, r = w & 15;
        biasP[t] = B[nt * 32 + (r & 3) + 8 * (r >> 2) + 4 * h];
    }
}

// ---------------------------------------------------------------------------
// Kernel 1 v3: fully register-resident MLP.  One wave per WG, 32 batch rows.
// Swapped orientation Y^T = W^T @ X^T via mfma_f32_32x32x16_bf16:
//   A-op = weight frag (prepped layout), B-op = activations (batch=lane&31,
//   k=(lane>>5)*8+j), D: batch=lane&31 (invariant!), feature=(r&3)+8(r>>2)+4h.
// Layer chaining: pack D pairs to bf16, one shfl_xor(32) per quad, select.
// NO LDS, NO barriers.
// ---------------------------------------------------------------------------
template<int K, int N, bool RELU>
__device__ inline void layerR(const short* __restrict__ wp,
                              const float* __restrict__ bp,
                              const u32x4* __restrict__ inF,
                              u32x4* __restrict__ outF,
                              int lane, int h)
{
    constexpr int KT = K / 16, NT = N / 32;
#pragma unroll
    for (int nt = 0; nt < NT; ++nt) {
        f32x16 a;
#pragma unroll
        for (int r = 0; r < 16; ++r) a[r] = 0.f;
#pragma unroll
        for (int kt = 0; kt < KT; ++kt) {
            short8 wf = *(const short8*)(wp + (nt * KT + kt) * 512 + lane * 8);
            a = __builtin_amdgcn_mfma_f32_32x32x16_bf16(
                    wf, __builtin_bit_cast(short8, inF[kt]), a, 0, 0, 0);
        }
        const float* bpp = bp + h * (N / 2) + nt * 16;
        unsigned q[8];
#pragma unroll
        for (int i = 0; i < 8; ++i) {
            float v0 = a[2 * i] + bpp[2 * i];
            float v1 = a[2 * i + 1] + bpp[2 * i + 1];
            if (RELU) { v0 = fmaxf(v0, 0.f); v1 = fmaxf(v1, 0.f); }
            q[i] = pkbf(v0, v1);
        }
        unsigned xq[8];
#pragma unroll
        for (int i = 0; i < 8; ++i) xq[i] = (unsigned)__shfl_xor((int)q[i], 32, 64);
        u32x4 fa, fb;
        if (h == 0) {
            fa[0] = q[0];  fa[1] = q[1];  fa[2] = xq[0]; fa[3] = xq[1];
            fb[0] = q[4];  fb[1] = q[5];  fb[2] = xq[4]; fb[3] = xq[5];
        } else {
            fa[0] = xq[2]; fa[1] = xq[3]; fa[2] = q[2];  fa[3] = q[3];
            fb[0] = xq[6]; fb[1] = xq[7]; fb[2] = q[6];  fb[3] = q[7];
        }
        outF[2 * nt]     = fa;
        outF[2 * nt + 1] = fb;
    }
}

template<int K>
__device__ inline void layerQ(const short* __restrict__ wp,
                              const float* __restrict__ bp,
                              const u32x4* __restrict__ inF,
                              short* __restrict__ qout,
                              int lane, int h, int r0)
{
    constexpr int KT = K / 16;
    f32x16 a;
#pragma unroll
    for (int r = 0; r < 16; ++r) a[r] = 0.f;
#pragma unroll
    for (int kt = 0; kt < KT; ++kt) {
        short8 wf = *(const short8*)(wp + kt * 512 + lane * 8);
        a = __builtin_amdgcn_mfma_f32_32x32x16_bf16(
                wf, __builtin_bit_cast(short8, inF[kt]), a, 0, 0, 0);
    }
    const float* bpp = bp + h * 16;
    short* qb = qout + (size_t)(r0 + (lane & 31)) * 32 + 4 * h;
    const int fo[8] = {0, 2, 8, 10, 16, 18, 24, 26};
#pragma unroll
    for (int i = 0; i < 8; ++i) {
        float v0 = a[2 * i] + bpp[2 * i];
        float v1 = a[2 * i + 1] + bpp[2 * i + 1];
        *(unsigned*)(qb + fo[i]) = pkbf(v0, v1);
    }
}

__global__ void __launch_bounds__(64, 2) mlp_kernel(
    const float* __restrict__ hid,
    const short* __restrict__ wp,
    const float* __restrict__ biasP,
    short* __restrict__ qout)
{
    const int lane = threadIdx.x;
    const int h = lane >> 5, b = lane & 31;
    const int r0 = blockIdx.x * 32;

    u32x4 A[16], B[16], C[8], D[4], E[2];
    const float* hb = hid + (size_t)(r0 + b) * 256 + h * 8;
#pragma unroll
    for (int kt = 0; kt < 16; ++kt) {
        float4 x = *(const float4*)(hb + kt * 16);
        float4 y = *(const float4*)(hb + kt * 16 + 4);
        u32x4 f;
        f[0] = pkbf(x.x, x.y); f[1] = pkbf(x.z, x.w);
        f[2] = pkbf(y.x, y.y); f[3] = pkbf(y.z, y.w);
        A[kt] = f;
    }
    layerR<256, 256, true>(wp,          biasP,       A, B, lane, h);
    layerR<256, 128, true>(wp + 65536,  biasP + 256, B, C, lane, h);
    layerR<128,  64, true>(wp + 98304,  biasP + 384, C, D, lane, h);
    layerR< 64,  32, true>(wp + 106496, biasP + 448, D, E, lane, h);
    layerQ< 32>           (wp + 108544, biasP + 480, E, qout, lane, h, r0);
}

// ---------------------------------------------------------------------------
// Kernel 2 v4 (unchanged from R5, proven): single-wave WG, 16 el/wave.
// ---------------------------------------------------------------------------
__global__ void __launch_bounds__(64) conv_attn_kernel(
    const float* __restrict__ Xg,
    const short* __restrict__ weffT,
    const float* __restrict__ beff,
    const short* __restrict__ aw0T, const float* __restrict__ ab0,
    const short* __restrict__ aw1T, const float* __restrict__ ab1,
    const float* __restrict__ sTab,
    const short* __restrict__ qb16,
    float* __restrict__ out)
{
    __shared__ __align__(16) unsigned char spool[14096];
    short* sKc = (short*)spool;
    short* sVc = (short*)(spool + 3200);
    short* sX  = (short*)spool;
    short* sQ  = (short*)(spool + 9600);
    float* sS  = (float*)(spool + 10624);
    short* sA  = (short*)(spool + 11024);
    short* sH  = (short*)(spool + 13072);

    const int lane   = threadIdx.x;
    const int lanelo = lane & 15;
    const int g      = lane >> 4;
    const int blk    = blockIdx.x;

    {
        short8 qv = *(const short8*)(qb16 + blk * 512 + lane * 8);
        *(short8*)(sQ + lane * 8) = qv;
    }
    if (lane < 50) {
        float2 t = *(const float2*)(sTab + lane * 2);
        sS[lane * 2]     = t.x;
        sS[lane * 2 + 1] = t.y;
    }
#pragma unroll
    for (int i = 0; i < 4; ++i) {
        int t = lane + i * 64;
        if (t < 208) {
            int r = t / 13, c = 147 + (t - r * 13);
            int ch = c >> 3;
            sX[r * 192 + ((ch ^ (r & 7)) << 3) + (c & 7)] = 0;
        }
    }
    {
        const float* xb = Xg + (size_t)blk * 2352;
#define PUTX(IDX, F) { int _i = (IDX); int _r = _i / 147; int _c = _i - _r * 147; \
        int _ch = _c >> 3; sX[_r * 192 + ((_ch ^ (_r & 7)) << 3) + (_c & 7)] = f2bf(F); }
#pragma unroll
        for (int i = 0; i < 10; ++i) {
            int idx4 = lane + i * 64;
            if (idx4 < 588) {
                float4 v = reinterpret_cast<const float4*>(xb)[idx4];
                int base = idx4 * 4;
                PUTX(base + 0, v.x)
                PUTX(base + 1, v.y)
                PUTX(base + 2, v.z)
                PUTX(base + 3, v.w)
            }
        }
#undef PUTX
    }

    short8 af[5];
#pragma unroll
    for (int kt = 0; kt < 5; ++kt) {
        int phys = (kt * 4 + g) ^ (lanelo & 7);
        af[kt] = *(const short8*)(sX + lanelo * 192 + phys * 8);
    }

    short8 bf[2][5];
    {
        const short* wb = weffT + lanelo * 160 + g * 8;
#pragma unroll
        for (int kt = 0; kt < 5; ++kt) bf[0][kt] = *(const short8*)(wb + kt * 32);
    }
#pragma unroll
    for (int nt = 0; nt < 19; ++nt) {
        if (nt + 1 < 19) {
            const short* wb = weffT + ((nt + 1) * 16 + lanelo) * 160 + g * 8;
#pragma unroll
            for (int kt = 0; kt < 5; ++kt)
                bf[(nt + 1) & 1][kt] = *(const short8*)(wb + kt * 32);
        }
        f32x4 a; a[0] = 0.f; a[1] = 0.f; a[2] = 0.f; a[3] = 0.f;
#pragma unroll
        for (int kt = 0; kt < 5; ++kt)
            a = __builtin_amdgcn_mfma_f32_16x16x32_bf16(af[kt], bf[nt & 1][kt], a, 0, 0, 0);
        int n = nt * 16 + lanelo;
        if (n < 300) {
            float bb = beff[n];
            int p = n / 12, c = n - p * 12;
#pragma unroll
            for (int j = 0; j < 4; ++j) {
                int el = g * 4 + j;
                float v = a[j] + bb;
                if (c < 4) sKc[el * 100 + p * 4 + c]       = f2bf(v);
                else       sVc[el * 200 + p * 8 + (c - 4)] = f2bf(v);
            }
        }
    }

    {
        const int el = lane >> 2, qi = lane & 3;
        short8 qv = *(const short8*)(sQ + el * 32 + qi * 8);
        float qf[8];
#pragma unroll
        for (int i = 0; i < 8; ++i) qf[i] = b2f(qv[i]);

        float lg[25];
        float mx = -1e30f;
#pragma unroll
        for (int p = 0; p < 25; ++p) {
            short4v kv = *(const short4v*)(sKc + el * 100 + p * 4);
            const float* sp = sS + p * 4;
            float s = b2f(kv[0]) * qf[0] + b2f(kv[1]) * qf[1]
                    + b2f(kv[2]) * qf[2] + b2f(kv[3]) * qf[3]
                    + sp[0] * qf[4] + sp[1] * qf[5]
                    + sp[2] * qf[6] + sp[3] * qf[7];
            lg[p] = s;
            mx = fmaxf(mx, s);
        }
        float sum = 0.f;
#pragma unroll
        for (int p = 0; p < 25; ++p) { lg[p] = __expf(lg[p] - mx); sum += lg[p]; }
        float inv = 1.f / sum;

        float o[12];
#pragma unroll
        for (int d = 0; d < 12; ++d) o[d] = 0.f;
#pragma unroll
        for (int p = 0; p < 25; ++p) {
            float w = lg[p];
            short4v v0 = *(const short4v*)(sVc + el * 200 + p * 8);
            short4v v1 = *(const short4v*)(sVc + el * 200 + p * 8 + 4);
            const float* sp = sS + p * 4;
            o[0] += w * b2f(v0[0]); o[1] += w * b2f(v0[1]);
            o[2] += w * b2f(v0[2]); o[3] += w * b2f(v0[3]);
            o[4] += w * b2f(v1[0]); o[5] += w * b2f(v1[1]);
            o[6] += w * b2f(v1[2]); o[7] += w * b2f(v1[3]);
            o[8]  += w * sp[0]; o[9]  += w * sp[1];
            o[10] += w * sp[2]; o[11] += w * sp[3];
        }
#pragma unroll
        for (int d = 0; d < 12; ++d) {
            int col = qi * 12 + d;
            int ch = col >> 3;
            sA[el * 64 + ((ch ^ (el & 7)) << 3) + (col & 7)] = f2bf(o[d] * inv);
        }
#pragma unroll
        for (int t = 0; t < 4; ++t) {
            int col = 48 + qi * 4 + t;
            int ch = col >> 3;
            sA[el * 64 + ((ch ^ (el & 7)) << 3) + (col & 7)] = 0;
        }
    }

    {
        short8 aa0, aa1;
        {
            int p0 = (0 * 4 + g) ^ (lanelo & 7);
            int p1 = (1 * 4 + g) ^ (lanelo & 7);
            aa0 = *(const short8*)(sA + lanelo * 64 + p0 * 8);
            aa1 = *(const short8*)(sA + lanelo * 64 + p1 * 8);
        }
#pragma unroll
        for (int nt2 = 0; nt2 < 2; ++nt2) {
            int n = nt2 * 16 + lanelo;
            short8 bw0 = *(const short8*)(aw0T + n * 64 + g * 8);
            short8 bw1 = *(const short8*)(aw0T + n * 64 + 32 + g * 8);
            f32x4 hh; hh[0] = 0.f; hh[1] = 0.f; hh[2] = 0.f; hh[3] = 0.f;
            hh = __builtin_amdgcn_mfma_f32_16x16x32_bf16(aa0, bw0, hh, 0, 0, 0);
            hh = __builtin_amdgcn_mfma_f32_16x16x32_bf16(aa1, bw1, hh, 0, 0, 0);
            float bb = ab0[n];
#pragma unroll
            for (int j = 0; j < 4; ++j) {
                int row = g * 4 + j;
                int ch = n >> 3;
                float v = fmaxf(hh[j] + bb, 0.f);
                sH[row * 32 + ((ch ^ (row & 3)) << 3) + (n & 7)] = f2bf(v);
            }
        }
    }

    {
        short8 ah;
        {
            int ph = (g ^ (lanelo & 3));
            ah = *(const short8*)(sH + lanelo * 32 + ph * 8);
        }
#pragma unroll
        for (int nt3 = 0; nt3 < 4; ++nt3) {
            int n = nt3 * 16 + lanelo;
            short8 bw = *(const short8*)(aw1T + n * 32 + g * 8);
            f32x4 oacc; oacc[0] = 0.f; oacc[1] = 0.f; oacc[2] = 0.f; oacc[3] = 0.f;
            oacc = __builtin_amdgcn_mfma_f32_16x16x32_bf16(ah, bw, oacc, 0, 0, 0);
            float bb = ab1[n];
#pragma unroll
            for (int j = 0; j < 4; ++j) {
                int el = g * 4 + j;
                out[((size_t)blk * 16 + el) * 64 + n] = oacc[j] + bb;
            }
        }
    }
}

// ---------------------------------------------------------------------------

extern "C" void kernel_launch(void* const* d_in, const int* in_sizes, int n_in,
                              void* d_out, int out_size, void* d_ws, size_t ws_size,
                              hipStream_t stream)
{
    const float* X   = (const float*)d_in[0];
    const float* hid = (const float*)d_in[1];
    const float* c1w = (const float*)d_in[2];
    const float* c1b = (const float*)d_in[3];
    const float* c2w = (const float*)d_in[4];
    const float* c2b = (const float*)d_in[5];
    const float* qw0 = (const float*)d_in[6];
    const float* qb0 = (const float*)d_in[7];
    const float* qw1 = (const float*)d_in[8];
    const float* qb1 = (const float*)d_in[9];
    const float* qw2 = (const float*)d_in[10];
    const float* qb2 = (const float*)d_in[11];
    const float* qw3 = (const float*)d_in[12];
    const float* qb3 = (const float*)d_in[13];
    const float* qw4 = (const float*)d_in[14];
    const float* qb4 = (const float*)d_in[15];
    const float* aw0 = (const float*)d_in[16];
    const float* ab0 = (const float*)d_in[17];
    const float* aw1 = (const float*)d_in[18];
    const float* ab1 = (const float*)d_in[19];

    float* out   = (float*)d_out;
    short* qb16  = (short*)d_ws;
    short* wsW   = qb16 + (size_t)NB * 32;
    short* weffT = wsW + MLPW_CNT;
    float* beff  = (float*)(weffT + WEFF_CNT);
    short* aw0T  = (short*)(beff + 320);
    short* aw1T  = aw0T + 2048;
    float* sTab  = (float*)(aw1T + 2048);
    float* biasP = sTab + 100;

    hipLaunchKernelGGL(prep_kernel, dim3((PREP_TOT + 255) / 256), dim3(256), 0, stream,
                       qw0, qw1, qw2, qw3, qw4, qb0, qb1, qb2, qb3, qb4,
                       c1w, c1b, c2w, c2b, aw0, aw1,
                       wsW, weffT, beff, aw0T, aw1T, sTab, biasP);
    hipLaunchKernelGGL(mlp_kernel, dim3(NB / 32), dim3(64), 0, stream,
                       hid, wsW, biasP, qb16);
    hipLaunchKernelGGL(conv_attn_kernel, dim3(NB / 16), dim3(64), 0, stream,
                       X, weffT, beff, aw0T, ab0, aw1T, ab1, sTab, qb16, out);
}